// Round 1
// baseline (1695.197 us; speedup 1.0000x reference)
//
#include <hip/hip_runtime.h>
#include <stdint.h>

typedef __bf16 bf16_t;
typedef bf16_t bf16x8 __attribute__((ext_vector_type(8)));
typedef float f32x4 __attribute__((ext_vector_type(4)));

typedef unsigned int u32;
typedef __attribute__((address_space(1))) const u32 gu32;
typedef __attribute__((address_space(3))) u32 lu32;

#define LN_EPS 1e-5f
#define EPS_ 1e-8f
#define SCALE_ 0.04419417382415922f  // 512^-0.5

__device__ __forceinline__ float wave_red_sum(float v) {
#pragma unroll
  for (int off = 32; off > 0; off >>= 1) v += __shfl_xor(v, off, 64);
  return v;
}

// ---------------- prep: transpose weights, pack bias, copy slots ----------------
__global__ __launch_bounds__(256) void prep_kernel(
    const float* __restrict__ Wk, const float* __restrict__ Wv,
    const float* __restrict__ bk, const float* __restrict__ bv,
    const float* __restrict__ wih, const float* __restrict__ whh,
    const float* __restrict__ slots_init,
    bf16_t* __restrict__ BT, float* __restrict__ wihT, float* __restrict__ whhT,
    float* __restrict__ biasc, float* __restrict__ slots)
{
  int idx = blockIdx.x * 256 + threadIdx.x;
  if (idx < 524288) {            // BT[n][kk] = W[kk][n], n in [0,1024), kk in [0,512)
    int kk = idx & 511, n = idx >> 9;
    float v = (n < 512) ? Wk[kk * 512 + n] : Wv[kk * 512 + (n - 512)];
    BT[n * 512 + kk] = (bf16_t)v;
    return;
  }
  idx -= 524288;
  if (idx < 786432) {            // wihT[d][g] = wih[g][d]
    int g = idx % 1536, d = idx / 1536;
    wihT[d * 1536 + g] = wih[g * 512 + d];
    return;
  }
  idx -= 786432;
  if (idx < 786432) {
    int g = idx % 1536, d = idx / 1536;
    whhT[d * 1536 + g] = whh[g * 512 + d];
    return;
  }
  idx -= 786432;
  if (idx < 1024) {
    biasc[idx] = (idx < 512) ? bk[idx] : bv[idx - 512];
    return;
  }
  idx -= 1024;
  if (idx < 32768) slots[idx] = slots_init[idx];
}

// ---------------- LN(inputs) -> x bf16 ----------------
__global__ __launch_bounds__(256) void ln_input(
    const float* __restrict__ in, const float* __restrict__ g,
    const float* __restrict__ b, bf16_t* __restrict__ xbf)
{
  int w = threadIdx.x >> 6, lane = threadIdx.x & 63;
  size_t row = (size_t)blockIdx.x * 4 + w;
  const float4* rp = (const float4*)(in + row * 512);
  float4 a = rp[lane * 2], c = rp[lane * 2 + 1];
  float s1 = a.x + a.y + a.z + a.w + c.x + c.y + c.z + c.w;
  float s2 = a.x * a.x + a.y * a.y + a.z * a.z + a.w * a.w +
             c.x * c.x + c.y * c.y + c.z * c.z + c.w * c.w;
  s1 = wave_red_sum(s1);
  s2 = wave_red_sum(s2);
  float mean = s1 * (1.f / 512.f);
  float var = s2 * (1.f / 512.f) - mean * mean;
  float rstd = rsqrtf(var + LN_EPS);
  const float4* gp = (const float4*)g;
  const float4* bp = (const float4*)b;
  float4 g0 = gp[lane * 2], g1 = gp[lane * 2 + 1];
  float4 b0 = bp[lane * 2], b1v = bp[lane * 2 + 1];
  bf16x8 o;
  o[0] = (bf16_t)((a.x - mean) * rstd * g0.x + b0.x);
  o[1] = (bf16_t)((a.y - mean) * rstd * g0.y + b0.y);
  o[2] = (bf16_t)((a.z - mean) * rstd * g0.z + b0.z);
  o[3] = (bf16_t)((a.w - mean) * rstd * g0.w + b0.w);
  o[4] = (bf16_t)((c.x - mean) * rstd * g1.x + b1v.x);
  o[5] = (bf16_t)((c.y - mean) * rstd * g1.y + b1v.y);
  o[6] = (bf16_t)((c.z - mean) * rstd * g1.z + b1v.z);
  o[7] = (bf16_t)((c.w - mean) * rstd * g1.w + b1v.w);
  *(bf16x8*)(xbf + row * 512 + lane * 8) = o;
}

// ---------------- bf16 MFMA GEMM: [65536,512] x [512,1024] -> k(fp32), v(bf16) ----------------
__global__ __launch_bounds__(256) void gemm_kv(
    const bf16_t* __restrict__ xbf, const bf16_t* __restrict__ BT,
    const float* __restrict__ biasc, float* __restrict__ out_k,
    bf16_t* __restrict__ vbf)
{
  __shared__ bf16_t As[128 * 32];
  __shared__ bf16_t Bs[128 * 32];
  const int tid = threadIdx.x;
  const int lane = tid & 63;
  const int w = tid >> 6;
  const int quad = lane >> 4;
  const int l16 = lane & 15;
  const int m0 = blockIdx.x * 128;
  const int n0 = blockIdx.y * 128;
  const int mb = (w & 1) * 64;
  const int nb = (w >> 1) * 64;

  f32x4 acc[4][4] = {};

  for (int kk = 0; kk < 512; kk += 32) {
#pragma unroll
    for (int r = 0; r < 2; ++r) {
      int t = tid + r * 256;
      int rr = t >> 2;
      int cc = (t & 3) * 8;
      const bf16_t* ga = xbf + (size_t)(m0 + rr) * 512 + kk + cc;
      __builtin_amdgcn_global_load_lds((gu32*)ga, (lu32*)&As[t * 8], 16, 0, 0);
      const bf16_t* gb = BT + (size_t)(n0 + rr) * 512 + kk + cc;
      __builtin_amdgcn_global_load_lds((gu32*)gb, (lu32*)&Bs[t * 8], 16, 0, 0);
    }
    __syncthreads();
    bf16x8 af[4], bfr[4];
#pragma unroll
    for (int mt = 0; mt < 4; ++mt)
      af[mt] = *(const bf16x8*)&As[(mb + mt * 16 + l16) * 32 + quad * 8];
#pragma unroll
    for (int nt = 0; nt < 4; ++nt)
      bfr[nt] = *(const bf16x8*)&Bs[(nb + nt * 16 + l16) * 32 + quad * 8];
#pragma unroll
    for (int mt = 0; mt < 4; ++mt)
#pragma unroll
      for (int nt = 0; nt < 4; ++nt)
        acc[mt][nt] = __builtin_amdgcn_mfma_f32_16x16x32_bf16(af[mt], bfr[nt], acc[mt][nt], 0, 0, 0);
    __syncthreads();
  }

#pragma unroll
  for (int nt = 0; nt < 4; ++nt) {
    int n_g = n0 + nb + nt * 16 + l16;
    float bias = biasc[n_g];
#pragma unroll
    for (int mt = 0; mt < 4; ++mt) {
#pragma unroll
      for (int r = 0; r < 4; ++r) {
        int m_g = m0 + mb + mt * 16 + quad * 4 + r;
        float val = acc[mt][nt][r] + bias;
        if (n_g < 512) {
          out_k[(size_t)m_g * 512 + n_g] = val;
        } else {
          vbf[(size_t)m_g * 512 + (n_g - 512)] = (bf16_t)val;
        }
      }
    }
  }
}

// ---------------- per-iteration: s = LN(slots), q = s@Wq + bq; zero accumulators ----------------
__global__ __launch_bounds__(256) void slot_q_kernel(
    const float* __restrict__ slots, const float* __restrict__ g, const float* __restrict__ bvec,
    const float* __restrict__ Wq, const float* __restrict__ bq,
    float* __restrict__ qbuf, float* __restrict__ upd, float* __restrict__ rowsum,
    float* __restrict__ q_out, int last)
{
  __shared__ float s[512];
  __shared__ float red1[4], red2[4];
  int tid = threadIdx.x, row = blockIdx.x;
  float v0 = slots[row * 512 + tid], v1 = slots[row * 512 + 256 + tid];
  float s1 = v0 + v1, s2 = v0 * v0 + v1 * v1;
  s1 = wave_red_sum(s1);
  s2 = wave_red_sum(s2);
  int w = tid >> 6, lane = tid & 63;
  if (lane == 0) { red1[w] = s1; red2[w] = s2; }
  __syncthreads();
  s1 = red1[0] + red1[1] + red1[2] + red1[3];
  s2 = red2[0] + red2[1] + red2[2] + red2[3];
  float mean = s1 * (1.f / 512.f);
  float var = s2 * (1.f / 512.f) - mean * mean;
  float rstd = rsqrtf(var + LN_EPS);
  s[tid] = (v0 - mean) * rstd * g[tid] + bvec[tid];
  s[tid + 256] = (v1 - mean) * rstd * g[tid + 256] + bvec[tid + 256];
  // zero this iteration's accumulators (ws is poisoned 0xAA before each launch)
  upd[row * 512 + tid] = 0.f;
  upd[row * 512 + 256 + tid] = 0.f;
  if (tid == 0) rowsum[row] = 0.f;
  __syncthreads();
  for (int n = tid; n < 512; n += 256) {
    float acc = bq[n];
#pragma unroll 4
    for (int d = 0; d < 512; ++d) acc += s[d] * Wq[d * 512 + n];
    qbuf[row * 512 + n] = acc;
    if (last) q_out[row * 512 + n] = acc;
  }
}

// ---------------- fused dots -> slot-softmax -> weighted-v accumulate ----------------
__global__ __launch_bounds__(256) void attend_kernel(
    const float* __restrict__ kf, const bf16_t* __restrict__ vbf,
    const float* __restrict__ qbuf, float* __restrict__ upd,
    float* __restrict__ rowsum, float* __restrict__ attn_pre)
{
  int tid = threadIdx.x, w = tid >> 6, lane = tid & 63;
  int b = blockIdx.x >> 4, chunk = blockIdx.x & 15;
  int j0 = chunk * 128 + w * 32;
  const float4* q0p = (const float4*)(qbuf + (b * 2 + 0) * 512 + lane * 8);
  const float4* q1p = (const float4*)(qbuf + (b * 2 + 1) * 512 + lane * 8);
  float4 q0a = q0p[0], q0b = q0p[1], q1a = q1p[0], q1b = q1p[1];
  float u0[8] = {}, u1[8] = {};
  float rs0 = 0.f, rs1 = 0.f;
  for (int jj = 0; jj < 32; ++jj) {
    int j = j0 + jj;
    const float4* kp = (const float4*)(kf + (size_t)(b * 2048 + j) * 512 + lane * 8);
    float4 ka = kp[0], kb = kp[1];
    float d0 = ka.x * q0a.x + ka.y * q0a.y + ka.z * q0a.z + ka.w * q0a.w +
               kb.x * q0b.x + kb.y * q0b.y + kb.z * q0b.z + kb.w * q0b.w;
    float d1 = ka.x * q1a.x + ka.y * q1a.y + ka.z * q1a.z + ka.w * q1a.w +
               kb.x * q1b.x + kb.y * q1b.y + kb.z * q1b.z + kb.w * q1b.w;
    d0 = wave_red_sum(d0) * SCALE_;
    d1 = wave_red_sum(d1) * SCALE_;
    float mx = fmaxf(d0, d1);
    float e0 = __expf(d0 - mx), e1 = __expf(d1 - mx);
    float inv = 1.f / (e0 + e1);
    float p0 = e0 * inv, p1 = e1 * inv;
    rs0 += p0;
    rs1 += p1;
    bf16x8 vv = *(const bf16x8*)(vbf + (size_t)(b * 2048 + j) * 512 + lane * 8);
#pragma unroll
    for (int t = 0; t < 8; ++t) {
      float vf = (float)vv[t];
      u0[t] += p0 * vf;
      u1[t] += p1 * vf;
    }
    if (lane == 0) {
      attn_pre[(b * 2 + 0) * 2048 + j] = p0;
      attn_pre[(b * 2 + 1) * 2048 + j] = p1;
    }
  }
#pragma unroll
  for (int t = 0; t < 8; ++t) {
    atomicAdd(&upd[(b * 2 + 0) * 512 + lane * 8 + t], u0[t]);
    atomicAdd(&upd[(b * 2 + 1) * 512 + lane * 8 + t], u1[t]);
  }
  if (lane == 0) {
    atomicAdd(&rowsum[b * 2 + 0], rs0);
    atomicAdd(&rowsum[b * 2 + 1], rs1);
  }
}

// ---------------- GRU + residual MLP per slot row ----------------
__global__ __launch_bounds__(512) void finalize_kernel(
    float* __restrict__ slots, const float* __restrict__ upd, const float* __restrict__ rowsum,
    const float* __restrict__ wihT, const float* __restrict__ whhT,
    const float* __restrict__ bih, const float* __restrict__ bhh,
    const float* __restrict__ lnf_g, const float* __restrict__ lnf_b,
    const float* __restrict__ W1, const float* __restrict__ b1,
    const float* __restrict__ W2, const float* __restrict__ b2,
    float* __restrict__ slots_out, int last)
{
  __shared__ float u[512], h[512], gx[1536], gh[1536], act[512], hln[512];
  __shared__ float red1[8], red2[8];
  int tid = threadIdx.x, row = blockIdx.x;
  float inv = 1.f / (rowsum[row] + EPS_);
  u[tid] = upd[row * 512 + tid] * inv;
  float hv_in = slots[row * 512 + tid];
  h[tid] = hv_in;
  __syncthreads();
#pragma unroll 1
  for (int gi = 0; gi < 3; ++gi) {
    int gidx = gi * 512 + tid;
    float ax = bih[gidx], ah = bhh[gidx];
#pragma unroll 4
    for (int d = 0; d < 512; ++d) {
      ax += u[d] * wihT[d * 1536 + gidx];
      ah += h[d] * whhT[d * 1536 + gidx];
    }
    gx[gidx] = ax;
    gh[gidx] = ah;
  }
  __syncthreads();
  float r_ = 1.f / (1.f + __expf(-(gx[tid] + gh[tid])));
  float z_ = 1.f / (1.f + __expf(-(gx[512 + tid] + gh[512 + tid])));
  float n_ = tanhf(gx[1024 + tid] + r_ * gh[1024 + tid]);
  float hn = (1.f - z_) * n_ + z_ * hv_in;
  float s1 = wave_red_sum(hn), s2 = wave_red_sum(hn * hn);
  int w = tid >> 6, lane = tid & 63;
  if (lane == 0) { red1[w] = s1; red2[w] = s2; }
  __syncthreads();
  s1 = 0.f; s2 = 0.f;
#pragma unroll
  for (int i = 0; i < 8; ++i) { s1 += red1[i]; s2 += red2[i]; }
  float mean = s1 * (1.f / 512.f);
  float var = s2 * (1.f / 512.f) - mean * mean;
  float rstd = rsqrtf(var + LN_EPS);
  hln[tid] = (hn - mean) * rstd * lnf_g[tid] + lnf_b[tid];
  __syncthreads();
  float a = b1[tid];
#pragma unroll 4
  for (int d = 0; d < 512; ++d) a += hln[d] * W1[d * 512 + tid];
  act[tid] = fmaxf(a, 0.f);
  __syncthreads();
  float o = b2[tid];
#pragma unroll 4
  for (int j = 0; j < 512; ++j) o += act[j] * W2[j * 512 + tid];
  float res = hn + o;
  slots[row * 512 + tid] = res;
  if (last) slots_out[row * 512 + tid] = res;
}

// ---------------- attn = attn_pre / (rowsum + eps) ----------------
__global__ __launch_bounds__(256) void norm_attn(
    const float* __restrict__ attn_pre, const float* __restrict__ rowsum,
    float* __restrict__ attn_out)
{
  int idx = blockIdx.x * 256 + threadIdx.x;  // < 131072
  int row = idx >> 11;
  attn_out[idx] = attn_pre[idx] / (rowsum[row] + EPS_);
}

extern "C" void kernel_launch(void* const* d_in, const int* in_sizes, int n_in,
                              void* d_out, int out_size, void* d_ws, size_t ws_size,
                              hipStream_t stream)
{
  const float* inputs     = (const float*)d_in[0];
  const float* slots_init = (const float*)d_in[1];
  const float* Wq   = (const float*)d_in[2];
  const float* bq   = (const float*)d_in[3];
  const float* Wk   = (const float*)d_in[4];
  const float* bk   = (const float*)d_in[5];
  const float* Wv   = (const float*)d_in[6];
  const float* bv   = (const float*)d_in[7];
  const float* ln_in_g = (const float*)d_in[8];
  const float* ln_in_b = (const float*)d_in[9];
  const float* ln_s_g  = (const float*)d_in[10];
  const float* ln_s_b  = (const float*)d_in[11];
  const float* ln_f_g  = (const float*)d_in[12];
  const float* ln_f_b  = (const float*)d_in[13];
  const float* wih  = (const float*)d_in[14];
  const float* whh  = (const float*)d_in[15];
  const float* bih  = (const float*)d_in[16];
  const float* bhh  = (const float*)d_in[17];
  const float* W1   = (const float*)d_in[18];
  const float* b1   = (const float*)d_in[19];
  const float* W2   = (const float*)d_in[20];
  const float* b2   = (const float*)d_in[21];

  float* out       = (float*)d_out;
  float* slots_out = out;                 // [32,2,512]   @ 0
  float* q_out     = out + 32768;         // [32,2,512]   @ 32768
  float* k_out     = out + 65536;         // [32,2048,512]@ 65536
  float* attn_out  = out + 33619968;      // [32,2,2048]  @ 33619968

  char* ws = (char*)d_ws;
  bf16_t* xbf   = (bf16_t*)(ws);                    // 67,108,864 B
  bf16_t* vbf   = (bf16_t*)(ws + 67108864);         // 67,108,864 B
  bf16_t* BT    = (bf16_t*)(ws + 134217728);        //  1,048,576 B
  float*  wihT  = (float*)(ws + 135266304);         //  3,145,728 B
  float*  whhT  = (float*)(ws + 138412032);         //  3,145,728 B
  float*  biasc = (float*)(ws + 141557760);         //      4,096 B
  float*  qbuf  = (float*)(ws + 141561856);         //    131,072 B
  float*  slots = (float*)(ws + 141692928);         //    131,072 B
  float*  upd   = (float*)(ws + 141824000);         //    131,072 B
  float*  rowsum= (float*)(ws + 141955072);         //        256 B
  float*  attnp = (float*)(ws + 141955328);         //    524,288 B  (total ~142.5 MB)

  prep_kernel<<<8324, 256, 0, stream>>>(Wk, Wv, bk, bv, wih, whh, slots_init,
                                        BT, wihT, whhT, biasc, slots);
  ln_input<<<16384, 256, 0, stream>>>(inputs, ln_in_g, ln_in_b, xbf);
  gemm_kv<<<dim3(512, 8), 256, 0, stream>>>(xbf, BT, biasc, k_out, vbf);
  for (int it = 0; it < 3; ++it) {
    int last = (it == 2);
    slot_q_kernel<<<64, 256, 0, stream>>>(slots, ln_s_g, ln_s_b, Wq, bq,
                                          qbuf, upd, rowsum, q_out, last);
    attend_kernel<<<512, 256, 0, stream>>>(k_out, vbf, qbuf, upd, rowsum, attnp);
    finalize_kernel<<<64, 512, 0, stream>>>(slots, upd, rowsum, wihT, whhT, bih, bhh,
                                            ln_f_g, ln_f_b, W1, b1, W2, b2,
                                            slots_out, last);
  }
  norm_attn<<<512, 256, 0, stream>>>(attnp, rowsum, attn_out);
}

// Round 2
// 1092.782 us; speedup vs baseline: 1.5513x; 1.5513x over previous
//
#include <hip/hip_runtime.h>
#include <stdint.h>

typedef __bf16 bf16_t;
typedef bf16_t bf16x8 __attribute__((ext_vector_type(8)));
typedef float f32x4 __attribute__((ext_vector_type(4)));

typedef unsigned int u32;
typedef __attribute__((address_space(1))) const u32 gu32;
typedef __attribute__((address_space(3))) u32 lu32;

#define LN_EPS 1e-5f
#define EPS_ 1e-8f
#define SCALE_ 0.04419417382415922f  // 512^-0.5

__device__ __forceinline__ float wave_red_sum(float v) {
#pragma unroll
  for (int off = 32; off > 0; off >>= 1) v += __shfl_xor(v, off, 64);
  return v;
}

// ---------------- prep: transpose weights, pack bias, copy slots ----------------
__global__ __launch_bounds__(256) void prep_kernel(
    const float* __restrict__ Wk, const float* __restrict__ Wv,
    const float* __restrict__ bk, const float* __restrict__ bv,
    const float* __restrict__ wih, const float* __restrict__ whh,
    const float* __restrict__ slots_init,
    bf16_t* __restrict__ BT, float* __restrict__ wihT, float* __restrict__ whhT,
    float* __restrict__ biasc, float* __restrict__ slots)
{
  int idx = blockIdx.x * 256 + threadIdx.x;
  if (idx < 524288) {            // BT[n][kk] = W[kk][n], n in [0,1024), kk in [0,512)
    int kk = idx & 511, n = idx >> 9;
    float v = (n < 512) ? Wk[kk * 512 + n] : Wv[kk * 512 + (n - 512)];
    BT[n * 512 + kk] = (bf16_t)v;
    return;
  }
  idx -= 524288;
  if (idx < 786432) {            // wihT[d][g] = wih[g][d]
    int g = idx % 1536, d = idx / 1536;
    wihT[d * 1536 + g] = wih[g * 512 + d];
    return;
  }
  idx -= 786432;
  if (idx < 786432) {
    int g = idx % 1536, d = idx / 1536;
    whhT[d * 1536 + g] = whh[g * 512 + d];
    return;
  }
  idx -= 786432;
  if (idx < 1024) {
    biasc[idx] = (idx < 512) ? bk[idx] : bv[idx - 512];
    return;
  }
  idx -= 1024;
  if (idx < 32768) slots[idx] = slots_init[idx];
}

// ---------------- LN(inputs) -> x bf16 ----------------
__global__ __launch_bounds__(256) void ln_input(
    const float* __restrict__ in, const float* __restrict__ g,
    const float* __restrict__ b, bf16_t* __restrict__ xbf)
{
  int w = threadIdx.x >> 6, lane = threadIdx.x & 63;
  size_t row = (size_t)blockIdx.x * 4 + w;
  const float4* rp = (const float4*)(in + row * 512);
  float4 a = rp[lane * 2], c = rp[lane * 2 + 1];
  float s1 = a.x + a.y + a.z + a.w + c.x + c.y + c.z + c.w;
  float s2 = a.x * a.x + a.y * a.y + a.z * a.z + a.w * a.w +
             c.x * c.x + c.y * c.y + c.z * c.z + c.w * c.w;
  s1 = wave_red_sum(s1);
  s2 = wave_red_sum(s2);
  float mean = s1 * (1.f / 512.f);
  float var = s2 * (1.f / 512.f) - mean * mean;
  float rstd = rsqrtf(var + LN_EPS);
  const float4* gp = (const float4*)g;
  const float4* bp = (const float4*)b;
  float4 g0 = gp[lane * 2], g1 = gp[lane * 2 + 1];
  float4 b0 = bp[lane * 2], b1v = bp[lane * 2 + 1];
  bf16x8 o;
  o[0] = (bf16_t)((a.x - mean) * rstd * g0.x + b0.x);
  o[1] = (bf16_t)((a.y - mean) * rstd * g0.y + b0.y);
  o[2] = (bf16_t)((a.z - mean) * rstd * g0.z + b0.z);
  o[3] = (bf16_t)((a.w - mean) * rstd * g0.w + b0.w);
  o[4] = (bf16_t)((c.x - mean) * rstd * g1.x + b1v.x);
  o[5] = (bf16_t)((c.y - mean) * rstd * g1.y + b1v.y);
  o[6] = (bf16_t)((c.z - mean) * rstd * g1.z + b1v.z);
  o[7] = (bf16_t)((c.w - mean) * rstd * g1.w + b1v.w);
  *(bf16x8*)(xbf + row * 512 + lane * 8) = o;
}

// ---------------- bf16 MFMA GEMM: [65536,512] x [512,1024] -> k(fp32 [+bf16]), v(bf16) ----------------
__global__ __launch_bounds__(256) void gemm_kv(
    const bf16_t* __restrict__ xbf, const bf16_t* __restrict__ BT,
    const float* __restrict__ biasc, float* __restrict__ out_k,
    bf16_t* __restrict__ vbf, bf16_t* __restrict__ kbf)
{
  __shared__ bf16_t As[128 * 32];
  __shared__ bf16_t Bs[128 * 32];
  const int tid = threadIdx.x;
  const int lane = tid & 63;
  const int w = tid >> 6;
  const int quad = lane >> 4;
  const int l16 = lane & 15;
  const int m0 = blockIdx.x * 128;
  const int n0 = blockIdx.y * 128;
  const int mb = (w & 1) * 64;
  const int nb = (w >> 1) * 64;

  f32x4 acc[4][4] = {};

  for (int kk = 0; kk < 512; kk += 32) {
#pragma unroll
    for (int r = 0; r < 2; ++r) {
      int t = tid + r * 256;
      int rr = t >> 2;
      int cc = (t & 3) * 8;
      const bf16_t* ga = xbf + (size_t)(m0 + rr) * 512 + kk + cc;
      __builtin_amdgcn_global_load_lds((gu32*)ga, (lu32*)&As[t * 8], 16, 0, 0);
      const bf16_t* gb = BT + (size_t)(n0 + rr) * 512 + kk + cc;
      __builtin_amdgcn_global_load_lds((gu32*)gb, (lu32*)&Bs[t * 8], 16, 0, 0);
    }
    __syncthreads();
    bf16x8 af[4], bfr[4];
#pragma unroll
    for (int mt = 0; mt < 4; ++mt)
      af[mt] = *(const bf16x8*)&As[(mb + mt * 16 + l16) * 32 + quad * 8];
#pragma unroll
    for (int nt = 0; nt < 4; ++nt)
      bfr[nt] = *(const bf16x8*)&Bs[(nb + nt * 16 + l16) * 32 + quad * 8];
#pragma unroll
    for (int mt = 0; mt < 4; ++mt)
#pragma unroll
      for (int nt = 0; nt < 4; ++nt)
        acc[mt][nt] = __builtin_amdgcn_mfma_f32_16x16x32_bf16(af[mt], bfr[nt], acc[mt][nt], 0, 0, 0);
    __syncthreads();
  }

#pragma unroll
  for (int nt = 0; nt < 4; ++nt) {
    int n_g = n0 + nb + nt * 16 + l16;
    float bias = biasc[n_g];
#pragma unroll
    for (int mt = 0; mt < 4; ++mt) {
#pragma unroll
      for (int r = 0; r < 4; ++r) {
        int m_g = m0 + mb + mt * 16 + quad * 4 + r;
        float val = acc[mt][nt][r] + bias;
        if (n_g < 512) {
          out_k[(size_t)m_g * 512 + n_g] = val;
          if (kbf) kbf[(size_t)m_g * 512 + n_g] = (bf16_t)val;
        } else {
          vbf[(size_t)m_g * 512 + (n_g - 512)] = (bf16_t)val;
        }
      }
    }
  }
}

// ---------------- per-iter: LN(slots) row + q = s@Wq + bq (row x half blocks) ----------------
__global__ __launch_bounds__(256) void q_ln_gemm(
    const float* __restrict__ slots, const float* __restrict__ g, const float* __restrict__ bvec,
    const float* __restrict__ Wq, const float* __restrict__ bq,
    float* __restrict__ qbuf, float* __restrict__ upd, float* __restrict__ rowsum,
    float* __restrict__ q_out, int last)
{
  __shared__ float s[512];
  __shared__ float red1[4], red2[4];
  int tid = threadIdx.x;
  int row = blockIdx.x >> 1, half = blockIdx.x & 1;
  float v0 = slots[row * 512 + tid], v1 = slots[row * 512 + 256 + tid];
  float s1 = v0 + v1, s2 = v0 * v0 + v1 * v1;
  s1 = wave_red_sum(s1);
  s2 = wave_red_sum(s2);
  int w = tid >> 6, lane = tid & 63;
  if (lane == 0) { red1[w] = s1; red2[w] = s2; }
  __syncthreads();
  s1 = red1[0] + red1[1] + red1[2] + red1[3];
  s2 = red2[0] + red2[1] + red2[2] + red2[3];
  float mean = s1 * (1.f / 512.f);
  float var = s2 * (1.f / 512.f) - mean * mean;
  float rstd = rsqrtf(var + LN_EPS);
  s[tid] = (v0 - mean) * rstd * g[tid] + bvec[tid];
  s[tid + 256] = (v1 - mean) * rstd * g[tid + 256] + bvec[tid + 256];
  if (half == 0) {
    upd[row * 512 + tid] = 0.f;
    upd[row * 512 + 256 + tid] = 0.f;
    if (tid == 0) rowsum[row] = 0.f;
  }
  __syncthreads();
  int col = half * 256 + tid;
  float acc = bq[col];
#pragma unroll 8
  for (int d = 0; d < 512; ++d) acc += s[d] * Wq[d * 512 + col];
  qbuf[row * 512 + col] = acc;
  if (last) q_out[row * 512 + col] = acc;
}

// ---------------- fused dots -> slot-softmax -> weighted-v accumulate ----------------
template <int USEBF>
__global__ __launch_bounds__(256) void attend_kernel(
    const float* __restrict__ kf, const bf16_t* __restrict__ kbf,
    const bf16_t* __restrict__ vbf,
    const float* __restrict__ qbuf, float* __restrict__ upd,
    float* __restrict__ rowsum, float* __restrict__ attn_pre)
{
  int tid = threadIdx.x, w = tid >> 6, lane = tid & 63;
  int b = blockIdx.x >> 4, chunk = blockIdx.x & 15;
  int j0 = chunk * 128 + w * 32;
  const float4* q0p = (const float4*)(qbuf + (b * 2 + 0) * 512 + lane * 8);
  const float4* q1p = (const float4*)(qbuf + (b * 2 + 1) * 512 + lane * 8);
  float4 q0a = q0p[0], q0b = q0p[1], q1a = q1p[0], q1b = q1p[1];
  float u0[8] = {}, u1[8] = {};
  float rs0 = 0.f, rs1 = 0.f;
  for (int jj = 0; jj < 32; ++jj) {
    int j = j0 + jj;
    float d0, d1;
    if (USEBF) {
      bf16x8 kk = *(const bf16x8*)(kbf + (size_t)(b * 2048 + j) * 512 + lane * 8);
      d0 = (float)kk[0] * q0a.x + (float)kk[1] * q0a.y + (float)kk[2] * q0a.z + (float)kk[3] * q0a.w +
           (float)kk[4] * q0b.x + (float)kk[5] * q0b.y + (float)kk[6] * q0b.z + (float)kk[7] * q0b.w;
      d1 = (float)kk[0] * q1a.x + (float)kk[1] * q1a.y + (float)kk[2] * q1a.z + (float)kk[3] * q1a.w +
           (float)kk[4] * q1b.x + (float)kk[5] * q1b.y + (float)kk[6] * q1b.z + (float)kk[7] * q1b.w;
    } else {
      const float4* kp = (const float4*)(kf + (size_t)(b * 2048 + j) * 512 + lane * 8);
      float4 ka = kp[0], kb = kp[1];
      d0 = ka.x * q0a.x + ka.y * q0a.y + ka.z * q0a.z + ka.w * q0a.w +
           kb.x * q0b.x + kb.y * q0b.y + kb.z * q0b.z + kb.w * q0b.w;
      d1 = ka.x * q1a.x + ka.y * q1a.y + ka.z * q1a.z + ka.w * q1a.w +
           kb.x * q1b.x + kb.y * q1b.y + kb.z * q1b.z + kb.w * q1b.w;
    }
    d0 = wave_red_sum(d0) * SCALE_;
    d1 = wave_red_sum(d1) * SCALE_;
    float mx = fmaxf(d0, d1);
    float e0 = __expf(d0 - mx), e1 = __expf(d1 - mx);
    float inv = 1.f / (e0 + e1);
    float p0 = e0 * inv, p1 = e1 * inv;
    rs0 += p0;
    rs1 += p1;
    bf16x8 vv = *(const bf16x8*)(vbf + (size_t)(b * 2048 + j) * 512 + lane * 8);
#pragma unroll
    for (int t = 0; t < 8; ++t) {
      float vf = (float)vv[t];
      u0[t] += p0 * vf;
      u1[t] += p1 * vf;
    }
    if (lane == 0) {
      attn_pre[(b * 2 + 0) * 2048 + j] = p0;
      attn_pre[(b * 2 + 1) * 2048 + j] = p1;
    }
  }
#pragma unroll
  for (int t = 0; t < 8; ++t) {
    atomicAdd(&upd[(b * 2 + 0) * 512 + lane * 8 + t], u0[t]);
    atomicAdd(&upd[(b * 2 + 1) * 512 + lane * 8 + t], u1[t]);
  }
  if (lane == 0) {
    atomicAdd(&rowsum[b * 2 + 0], rs0);
    atomicAdd(&rowsum[b * 2 + 1], rs1);
  }
}

// ---------------- gates: gx = u@wihT + bih, gh = h@whhT + bhh ----------------
// grid: 16 rowgroups x 48 colchunks (cc<24 -> gx, else gh); 4 rows x 64 cols per block
__global__ __launch_bounds__(256) void gates_kernel(
    const float* __restrict__ slots, const float* __restrict__ upd,
    const float* __restrict__ rowsum,
    const float* __restrict__ wihT, const float* __restrict__ whhT,
    const float* __restrict__ bih, const float* __restrict__ bhh,
    float* __restrict__ gx, float* __restrict__ gh)
{
  __shared__ float in[4][512];
  int tid = threadIdx.x;
  int rg = blockIdx.x / 48, cc = blockIdx.x % 48;
  int rl = tid >> 6, lane = tid & 63;
  int is_gh = (cc >= 24);
  int c = (is_gh ? cc - 24 : cc) * 64 + lane;
  int row = rg * 4 + rl;
  {
    const float* src = (is_gh ? slots : upd) + row * 512;
    float4 a = ((const float4*)src)[lane * 2];
    float4 bb = ((const float4*)src)[lane * 2 + 1];
    if (!is_gh) {
      float invs = 1.f / (rowsum[row] + EPS_);
      a.x *= invs; a.y *= invs; a.z *= invs; a.w *= invs;
      bb.x *= invs; bb.y *= invs; bb.z *= invs; bb.w *= invs;
    }
    *(float4*)&in[rl][lane * 8] = a;
    *(float4*)&in[rl][lane * 8 + 4] = bb;
  }
  __syncthreads();
  const float* __restrict__ W = is_gh ? whhT : wihT;
  float acc = is_gh ? bhh[c] : bih[c];
#pragma unroll 8
  for (int d = 0; d < 512; ++d) acc += in[rl][d] * W[d * 1536 + c];
  (is_gh ? gh : gx)[row * 1536 + c] = acc;
}

// ---------------- GRU elementwise + LN -> hnew, hln ----------------
__global__ __launch_bounds__(512) void gru_ln_kernel(
    const float* __restrict__ gx, const float* __restrict__ gh,
    const float* __restrict__ slots,
    const float* __restrict__ lnf_g, const float* __restrict__ lnf_b,
    float* __restrict__ hnew, float* __restrict__ hln)
{
  __shared__ float red1[8], red2[8];
  int tid = threadIdx.x, row = blockIdx.x;
  float gxr = gx[row * 1536 + tid], gxz = gx[row * 1536 + 512 + tid], gxn = gx[row * 1536 + 1024 + tid];
  float ghr = gh[row * 1536 + tid], ghz = gh[row * 1536 + 512 + tid], ghn = gh[row * 1536 + 1024 + tid];
  float h = slots[row * 512 + tid];
  float r_ = 1.f / (1.f + __expf(-(gxr + ghr)));
  float z_ = 1.f / (1.f + __expf(-(gxz + ghz)));
  float n_ = tanhf(gxn + r_ * ghn);
  float hn = (1.f - z_) * n_ + z_ * h;
  hnew[row * 512 + tid] = hn;
  float s1 = wave_red_sum(hn), s2 = wave_red_sum(hn * hn);
  int w = tid >> 6, lane = tid & 63;
  if (lane == 0) { red1[w] = s1; red2[w] = s2; }
  __syncthreads();
  s1 = 0.f; s2 = 0.f;
#pragma unroll
  for (int i = 0; i < 8; ++i) { s1 += red1[i]; s2 += red2[i]; }
  float mean = s1 * (1.f / 512.f);
  float var = s2 * (1.f / 512.f) - mean * mean;
  float rstd = rsqrtf(var + LN_EPS);
  hln[row * 512 + tid] = (hn - mean) * rstd * lnf_g[tid] + lnf_b[tid];
}

// ---------------- mlp1: act = relu(hln @ W1 + b1), 16 rg x 8 cc ----------------
__global__ __launch_bounds__(256) void mlp1_kernel(
    const float* __restrict__ hln, const float* __restrict__ W1,
    const float* __restrict__ b1, float* __restrict__ act)
{
  __shared__ float in[4][512];
  int tid = threadIdx.x;
  int rg = blockIdx.x >> 3, cc = blockIdx.x & 7;
  int rl = tid >> 6, lane = tid & 63;
  int col = cc * 64 + lane;
  int row = rg * 4 + rl;
  {
    const float* src = hln + row * 512;
    *(float4*)&in[rl][lane * 8] = ((const float4*)src)[lane * 2];
    *(float4*)&in[rl][lane * 8 + 4] = ((const float4*)src)[lane * 2 + 1];
  }
  __syncthreads();
  float acc = b1[col];
#pragma unroll 8
  for (int d = 0; d < 512; ++d) acc += in[rl][d] * W1[d * 512 + col];
  act[row * 512 + col] = fmaxf(acc, 0.f);
}

// ---------------- mlp2: slots = hnew + act @ W2 + b2 ----------------
__global__ __launch_bounds__(256) void mlp2_kernel(
    const float* __restrict__ act, const float* __restrict__ W2,
    const float* __restrict__ b2, const float* __restrict__ hnew,
    float* __restrict__ slots, float* __restrict__ slots_out, int last)
{
  __shared__ float in[4][512];
  int tid = threadIdx.x;
  int rg = blockIdx.x >> 3, cc = blockIdx.x & 7;
  int rl = tid >> 6, lane = tid & 63;
  int col = cc * 64 + lane;
  int row = rg * 4 + rl;
  {
    const float* src = act + row * 512;
    *(float4*)&in[rl][lane * 8] = ((const float4*)src)[lane * 2];
    *(float4*)&in[rl][lane * 8 + 4] = ((const float4*)src)[lane * 2 + 1];
  }
  __syncthreads();
  float acc = b2[col];
#pragma unroll 8
  for (int d = 0; d < 512; ++d) acc += in[rl][d] * W2[d * 512 + col];
  float res = hnew[row * 512 + col] + acc;
  slots[row * 512 + col] = res;
  if (last) slots_out[row * 512 + col] = res;
}

// ---------------- attn = attn_pre / (rowsum + eps) ----------------
__global__ __launch_bounds__(256) void norm_attn(
    const float* __restrict__ attn_pre, const float* __restrict__ rowsum,
    float* __restrict__ attn_out)
{
  int idx = blockIdx.x * 256 + threadIdx.x;  // < 131072
  int row = idx >> 11;
  attn_out[idx] = attn_pre[idx] / (rowsum[row] + EPS_);
}

extern "C" void kernel_launch(void* const* d_in, const int* in_sizes, int n_in,
                              void* d_out, int out_size, void* d_ws, size_t ws_size,
                              hipStream_t stream)
{
  const float* inputs     = (const float*)d_in[0];
  const float* slots_init = (const float*)d_in[1];
  const float* Wq   = (const float*)d_in[2];
  const float* bq   = (const float*)d_in[3];
  const float* Wk   = (const float*)d_in[4];
  const float* bk   = (const float*)d_in[5];
  const float* Wv   = (const float*)d_in[6];
  const float* bv   = (const float*)d_in[7];
  const float* ln_in_g = (const float*)d_in[8];
  const float* ln_in_b = (const float*)d_in[9];
  const float* ln_s_g  = (const float*)d_in[10];
  const float* ln_s_b  = (const float*)d_in[11];
  const float* ln_f_g  = (const float*)d_in[12];
  const float* ln_f_b  = (const float*)d_in[13];
  const float* wih  = (const float*)d_in[14];
  const float* whh  = (const float*)d_in[15];
  const float* bih  = (const float*)d_in[16];
  const float* bhh  = (const float*)d_in[17];
  const float* W1   = (const float*)d_in[18];
  const float* b1   = (const float*)d_in[19];
  const float* W2   = (const float*)d_in[20];
  const float* b2   = (const float*)d_in[21];

  float* out       = (float*)d_out;
  float* slots_out = out;                 // [32,2,512]   @ 0
  float* q_out     = out + 32768;         // [32,2,512]   @ 32768
  float* k_out     = out + 65536;         // [32,2048,512]@ 65536
  float* attn_out  = out + 33619968;      // [32,2,2048]  @ 33619968

  char* ws = (char*)d_ws;
  bf16_t* xbf   = (bf16_t*)(ws);                    // 67,108,864 B (dead after gemm_kv)
  // iteration-loop small buffers alias the dead xbf region:
  float*  gx    = (float*)(ws);                     //   393,216 B
  float*  gh    = (float*)(ws + 393216);            //   393,216 B
  float*  hnew  = (float*)(ws + 786432);            //   131,072 B
  float*  hln   = (float*)(ws + 917504);            //   131,072 B
  float*  act   = (float*)(ws + 1048576);           //   131,072 B
  bf16_t* vbf   = (bf16_t*)(ws + 67108864);         // 67,108,864 B
  bf16_t* BT    = (bf16_t*)(ws + 134217728);        //  1,048,576 B
  float*  wihT  = (float*)(ws + 135266304);         //  3,145,728 B
  float*  whhT  = (float*)(ws + 138412032);         //  3,145,728 B
  float*  biasc = (float*)(ws + 141557760);         //      4,096 B
  float*  qbuf  = (float*)(ws + 141561856);         //    131,072 B
  float*  slots = (float*)(ws + 141692928);         //    131,072 B
  float*  upd   = (float*)(ws + 141824000);         //    131,072 B
  float*  rowsum= (float*)(ws + 141955072);         //        256 B
  float*  attnp = (float*)(ws + 141955328);         //    524,288 B -> ends 142,479,616
  bool use_kbf = ws_size >= (size_t)142479616 + 67108864;
  bf16_t* kbf   = use_kbf ? (bf16_t*)(ws + 142479616) : nullptr;

  prep_kernel<<<8324, 256, 0, stream>>>(Wk, Wv, bk, bv, wih, whh, slots_init,
                                        BT, wihT, whhT, biasc, slots);
  ln_input<<<16384, 256, 0, stream>>>(inputs, ln_in_g, ln_in_b, xbf);
  gemm_kv<<<dim3(512, 8), 256, 0, stream>>>(xbf, BT, biasc, k_out, vbf, kbf);
  for (int it = 0; it < 3; ++it) {
    int last = (it == 2);
    q_ln_gemm<<<128, 256, 0, stream>>>(slots, ln_s_g, ln_s_b, Wq, bq,
                                       qbuf, upd, rowsum, q_out, last);
    if (use_kbf)
      attend_kernel<1><<<512, 256, 0, stream>>>(k_out, kbf, vbf, qbuf, upd, rowsum, attnp);
    else
      attend_kernel<0><<<512, 256, 0, stream>>>(k_out, kbf, vbf, qbuf, upd, rowsum, attnp);
    gates_kernel<<<768, 256, 0, stream>>>(slots, upd, rowsum, wihT, whhT, bih, bhh, gx, gh);
    gru_ln_kernel<<<64, 512, 0, stream>>>(gx, gh, slots, ln_f_g, ln_f_b, hnew, hln);
    mlp1_kernel<<<128, 256, 0, stream>>>(hln, W1, b1, act);
    mlp2_kernel<<<128, 256, 0, stream>>>(act, W2, b2, hnew, slots, slots_out, last);
  }
  norm_attn<<<512, 256, 0, stream>>>(attnp, rowsum, attn_out);
}

// Round 3
// 1038.176 us; speedup vs baseline: 1.6329x; 1.0526x over previous
//
#include <hip/hip_runtime.h>
#include <stdint.h>

typedef __bf16 bf16_t;
typedef bf16_t bf16x8 __attribute__((ext_vector_type(8)));
typedef float f32x4 __attribute__((ext_vector_type(4)));

typedef unsigned int u32;
typedef __attribute__((address_space(1))) const u32 gu32;
typedef __attribute__((address_space(3))) u32 lu32;

#define LN_EPS 1e-5f
#define EPS_ 1e-8f
#define SCALE_ 0.04419417382415922f  // 512^-0.5

__device__ __forceinline__ float wave_red_sum(float v) {
#pragma unroll
  for (int off = 32; off > 0; off >>= 1) v += __shfl_xor(v, off, 64);
  return v;
}

// ---------------- prep: LDS-tiled transposes (coalesced both sides) ----------------
// z=0: Wk -> BT rows [0,512);  z=1: Wv -> BT rows [512,1024)   (BT[n][kk], bf16)
// z=2: wih -> wihT[d][g];      z=3: whh -> whhT[d][g]          (fp32, 512x1536)
__global__ __launch_bounds__(256) void transpose_prep(
    const float* __restrict__ Wk, const float* __restrict__ Wv,
    const float* __restrict__ wih, const float* __restrict__ whh,
    bf16_t* __restrict__ BT, float* __restrict__ wihT, float* __restrict__ whhT)
{
  int z = blockIdx.z;
  if (z < 2 && blockIdx.y >= 16) return;
  const float* src = (z == 0) ? Wk : (z == 1) ? Wv : (z == 2) ? wih : whh;
  __shared__ float tile[32][33];
  int tx = threadIdx.x & 31, ty = threadIdx.x >> 5;  // 32 x 8
  int row0 = blockIdx.y * 32, col0 = blockIdx.x * 32;
#pragma unroll
  for (int i = 0; i < 4; ++i)
    tile[ty + 8 * i][tx] = src[(size_t)(row0 + ty + 8 * i) * 512 + col0 + tx];
  __syncthreads();
  if (z < 2) {
#pragma unroll
    for (int i = 0; i < 4; ++i)
      BT[(size_t)(z * 512 + col0 + ty + 8 * i) * 512 + row0 + tx] =
          (bf16_t)tile[tx][ty + 8 * i];
  } else {
    float* dst = (z == 2) ? wihT : whhT;
#pragma unroll
    for (int i = 0; i < 4; ++i)
      dst[(size_t)(col0 + ty + 8 * i) * 1536 + row0 + tx] = tile[tx][ty + 8 * i];
  }
}

// ---------------- small prep: biasc pack + slots init (into d_out) ----------------
__global__ __launch_bounds__(256) void small_prep(
    const float* __restrict__ bk, const float* __restrict__ bv,
    const float* __restrict__ slots_init,
    float* __restrict__ biasc, float* __restrict__ slots)
{
  int idx = blockIdx.x * 256 + threadIdx.x;  // < 33792
  if (idx < 1024) {
    biasc[idx] = (idx < 512) ? bk[idx] : bv[idx - 512];
  } else {
    int i = idx - 1024;  // < 32768
    slots[i] = slots_init[i];
  }
}

// ---------------- per-row LN stats of inputs: (mean, rstd) ----------------
__global__ __launch_bounds__(256) void ln_stats(
    const float* __restrict__ in, float2* __restrict__ stats)
{
  int w = threadIdx.x >> 6, lane = threadIdx.x & 63;
  size_t row = (size_t)blockIdx.x * 4 + w;
  const float4* rp = (const float4*)(in + row * 512);
  float4 a = rp[lane * 2], c = rp[lane * 2 + 1];
  float s1 = a.x + a.y + a.z + a.w + c.x + c.y + c.z + c.w;
  float s2 = a.x * a.x + a.y * a.y + a.z * a.z + a.w * a.w +
             c.x * c.x + c.y * c.y + c.z * c.z + c.w * c.w;
  s1 = wave_red_sum(s1);
  s2 = wave_red_sum(s2);
  if (lane == 0) {
    float mean = s1 * (1.f / 512.f);
    float var = s2 * (1.f / 512.f) - mean * mean;
    stats[row] = make_float2(mean, rsqrtf(var + LN_EPS));
  }
}

// ---------------- fused LN + bf16 MFMA GEMM: [65536,512] x [512,1024] ----------------
// n0<512 -> k (fp32 to d_out + bf16 to kbf); n0>=512 -> v (bf16 to vbf)
__global__ __launch_bounds__(256) void gemm_kv(
    const float* __restrict__ inp, const float2* __restrict__ stats,
    const float* __restrict__ lng, const float* __restrict__ lnb,
    const bf16_t* __restrict__ BT, const float* __restrict__ biasc,
    float* __restrict__ out_k, bf16_t* __restrict__ kbf, bf16_t* __restrict__ vbf)
{
  __shared__ __align__(16) char smem[16384];
  bf16_t* As = (bf16_t*)smem;            // 128 x 32 bf16, 8 KB
  bf16_t* Bs = (bf16_t*)(smem + 8192);   // 128 x 32 bf16, 8 KB
  float (*Cs)[132] = (float(*)[132])smem;  // 16 x 132 fp32, 8.4 KB (reuse)

  const int tid = threadIdx.x, lane = tid & 63, w = tid >> 6;
  const int quad = lane >> 4, l16 = lane & 15;
  const int n0 = blockIdx.x * 128;   // n-fastest: 8 consecutive blocks share A strip
  const int m0 = blockIdx.y * 128;
  const int mb = (w & 1) * 64, nb = (w >> 1) * 64;

  // A-staging mapping: each thread handles one row-half (16 cols)
  const int rr = tid >> 1, c16 = (tid & 1) * 16;
  const float2 st = stats[m0 + rr];
  const float mu = st.x, rs = st.y;
  const float* arow = inp + (size_t)(m0 + rr) * 512;

  f32x4 acc[4][4] = {};

  for (int kk = 0; kk < 512; kk += 32) {
    // ---- A: load fp32, apply LN, convert bf16, write LDS ----
    const float* ap = arow + kk + c16;
    f32x4 x0 = *(const f32x4*)(ap);
    f32x4 x1 = *(const f32x4*)(ap + 4);
    f32x4 x2 = *(const f32x4*)(ap + 8);
    f32x4 x3 = *(const f32x4*)(ap + 12);
    const float* gp = lng + kk + c16;
    const float* bp = lnb + kk + c16;
    f32x4 g0 = *(const f32x4*)(gp), g1 = *(const f32x4*)(gp + 4);
    f32x4 g2 = *(const f32x4*)(gp + 8), g3 = *(const f32x4*)(gp + 12);
    f32x4 b0 = *(const f32x4*)(bp), b1 = *(const f32x4*)(bp + 4);
    f32x4 b2 = *(const f32x4*)(bp + 8), b3 = *(const f32x4*)(bp + 12);
    bf16x8 oA, oB;
#pragma unroll
    for (int j = 0; j < 4; ++j) {
      oA[j]     = (bf16_t)((x0[j] - mu) * rs * g0[j] + b0[j]);
      oA[4 + j] = (bf16_t)((x1[j] - mu) * rs * g1[j] + b1[j]);
      oB[j]     = (bf16_t)((x2[j] - mu) * rs * g2[j] + b2[j]);
      oB[4 + j] = (bf16_t)((x3[j] - mu) * rs * g3[j] + b3[j]);
    }
    *(bf16x8*)&As[rr * 32 + c16] = oA;
    *(bf16x8*)&As[rr * 32 + c16 + 8] = oB;
    // ---- B: async global->LDS (width 16) ----
#pragma unroll
    for (int r = 0; r < 2; ++r) {
      int t = tid + r * 256;
      int rrB = t >> 2, ccB = (t & 3) * 8;
      const bf16_t* gb = BT + (size_t)(n0 + rrB) * 512 + kk + ccB;
      __builtin_amdgcn_global_load_lds((gu32*)gb, (lu32*)&Bs[t * 8], 16, 0, 0);
    }
    __syncthreads();
    bf16x8 af[4], bfr[4];
#pragma unroll
    for (int mt = 0; mt < 4; ++mt)
      af[mt] = *(const bf16x8*)&As[(mb + mt * 16 + l16) * 32 + quad * 8];
#pragma unroll
    for (int nt = 0; nt < 4; ++nt)
      bfr[nt] = *(const bf16x8*)&Bs[(nb + nt * 16 + l16) * 32 + quad * 8];
#pragma unroll
    for (int mt = 0; mt < 4; ++mt)
#pragma unroll
      for (int nt = 0; nt < 4; ++nt)
        acc[mt][nt] = __builtin_amdgcn_mfma_f32_16x16x32_bf16(af[mt], bfr[nt], acc[mt][nt], 0, 0, 0);
    __syncthreads();
  }

  // ---- epilogue: stage 16-row chunks in LDS, coalesced stores ----
  const int is_k = (n0 < 512);
  const int col4 = (tid * 4) & 127;
  const int row8 = tid >> 4;
  const int col8 = (tid * 8) & 127;
  for (int ci = 0; ci < 8; ++ci) {
    if ((ci < 4) == (mb == 0)) {
      int mt = ci & 3;
#pragma unroll
      for (int nt = 0; nt < 4; ++nt)
#pragma unroll
        for (int r = 0; r < 4; ++r)
          Cs[quad * 4 + r][nb + nt * 16 + l16] = acc[mt][nt][r];
    }
    __syncthreads();
    int rowbase = m0 + ci * 16;
    if (is_k) {
      f32x4 bias4 = *(const f32x4*)&biasc[n0 + col4];
#pragma unroll
      for (int p = 0; p < 2; ++p) {
        int f = p * 1024 + tid * 4;
        int row = f >> 7;
        f32x4 v = *(const f32x4*)&Cs[row][col4] + bias4;
        *(f32x4*)&out_k[(size_t)(rowbase + row) * 512 + n0 + col4] = v;
      }
      f32x4 ba = *(const f32x4*)&biasc[n0 + col8];
      f32x4 bb = *(const f32x4*)&biasc[n0 + col8 + 4];
      f32x4 v0 = *(const f32x4*)&Cs[row8][col8] + ba;
      f32x4 v1 = *(const f32x4*)&Cs[row8][col8 + 4] + bb;
      bf16x8 o;
#pragma unroll
      for (int j = 0; j < 4; ++j) { o[j] = (bf16_t)v0[j]; o[4 + j] = (bf16_t)v1[j]; }
      *(bf16x8*)&kbf[(size_t)(rowbase + row8) * 512 + n0 + col8] = o;
    } else {
      f32x4 ba = *(const f32x4*)&biasc[n0 + col8];
      f32x4 bb = *(const f32x4*)&biasc[n0 + col8 + 4];
      f32x4 v0 = *(const f32x4*)&Cs[row8][col8] + ba;
      f32x4 v1 = *(const f32x4*)&Cs[row8][col8 + 4] + bb;
      bf16x8 o;
#pragma unroll
      for (int j = 0; j < 4; ++j) { o[j] = (bf16_t)v0[j]; o[4 + j] = (bf16_t)v1[j]; }
      *(bf16x8*)&vbf[(size_t)(rowbase + row8) * 512 + (n0 - 512) + col8] = o;
    }
    __syncthreads();
  }
}

// ---------------- per-iter: LN(slots) + q = s@Wq + bq, 4-wave split-K ----------------
// grid 128 = 16 rowgroups x 8 colchunks; also zeroes upd/rowsum (cc==0)
__global__ __launch_bounds__(256) void q_fused(
    const float* __restrict__ slots, const float* __restrict__ g, const float* __restrict__ bvec,
    const float* __restrict__ Wq, const float* __restrict__ bq,
    float* __restrict__ qreg, float* __restrict__ upd, float* __restrict__ rowsum)
{
  __shared__ float in_s[4][512];
  __shared__ float part[4][4][64];
  int tid = threadIdx.x, w = tid >> 6, lane = tid & 63;
  int rg = blockIdx.x >> 3, cc = blockIdx.x & 7;
  int row = rg * 4 + w;
  // phase 1: wave w LNs row rg*4+w
  const float4* rp = (const float4*)(slots + row * 512);
  float4 a = rp[lane * 2], c = rp[lane * 2 + 1];
  float s1 = a.x + a.y + a.z + a.w + c.x + c.y + c.z + c.w;
  float s2 = a.x * a.x + a.y * a.y + a.z * a.z + a.w * a.w +
             c.x * c.x + c.y * c.y + c.z * c.z + c.w * c.w;
  s1 = wave_red_sum(s1);
  s2 = wave_red_sum(s2);
  float mean = s1 * (1.f / 512.f);
  float var = s2 * (1.f / 512.f) - mean * mean;
  float rstd = rsqrtf(var + LN_EPS);
  const float4* gp = (const float4*)g;
  const float4* bp = (const float4*)bvec;
  float4 g0 = gp[lane * 2], g1 = gp[lane * 2 + 1];
  float4 b0 = bp[lane * 2], b1v = bp[lane * 2 + 1];
  f32x4 o0, o1;
  o0[0] = (a.x - mean) * rstd * g0.x + b0.x;
  o0[1] = (a.y - mean) * rstd * g0.y + b0.y;
  o0[2] = (a.z - mean) * rstd * g0.z + b0.z;
  o0[3] = (a.w - mean) * rstd * g0.w + b0.w;
  o1[0] = (c.x - mean) * rstd * g1.x + b1v.x;
  o1[1] = (c.y - mean) * rstd * g1.y + b1v.y;
  o1[2] = (c.z - mean) * rstd * g1.z + b1v.z;
  o1[3] = (c.w - mean) * rstd * g1.w + b1v.w;
  *(f32x4*)&in_s[w][lane * 8] = o0;
  *(f32x4*)&in_s[w][lane * 8 + 4] = o1;
  if (cc == 0) {
    f32x4 z = {0.f, 0.f, 0.f, 0.f};
    *(f32x4*)&upd[row * 512 + lane * 8] = z;
    *(f32x4*)&upd[row * 512 + lane * 8 + 4] = z;
    if (lane == 0) rowsum[row] = 0.f;
  }
  __syncthreads();
  // phase 2: split-K GEMV
  int col = cc * 64 + lane;
  float acc[4] = {0.f, 0.f, 0.f, 0.f};
  for (int d = w * 128; d < w * 128 + 128; ++d) {
    float wv = Wq[d * 512 + col];
#pragma unroll
    for (int r = 0; r < 4; ++r) acc[r] += in_s[r][d] * wv;
  }
#pragma unroll
  for (int r = 0; r < 4; ++r) part[w][r][lane] = acc[r];
  __syncthreads();
  int r = tid >> 6;
  float s = part[0][r][lane] + part[1][r][lane] + part[2][r][lane] + part[3][r][lane]
          + bq[cc * 64 + lane];
  qreg[(rg * 4 + r) * 512 + cc * 64 + lane] = s;
}

// ---------------- fused dots -> slot-softmax -> weighted-v accumulate (bf16 k,v) ----------------
__global__ __launch_bounds__(256) void attend_kernel(
    const bf16_t* __restrict__ kbf, const bf16_t* __restrict__ vbf,
    const float* __restrict__ qbuf, float* __restrict__ upd,
    float* __restrict__ rowsum, float* __restrict__ attn_pre)
{
  int tid = threadIdx.x, w = tid >> 6, lane = tid & 63;
  int b = blockIdx.x >> 4, chunk = blockIdx.x & 15;
  int j0 = chunk * 128 + w * 32;
  const float4* q0p = (const float4*)(qbuf + (b * 2 + 0) * 512 + lane * 8);
  const float4* q1p = (const float4*)(qbuf + (b * 2 + 1) * 512 + lane * 8);
  float4 q0a = q0p[0], q0b = q0p[1], q1a = q1p[0], q1b = q1p[1];
  float u0[8] = {}, u1[8] = {};
  float rs0 = 0.f, rs1 = 0.f;
  for (int jj = 0; jj < 32; ++jj) {
    int j = j0 + jj;
    bf16x8 kk = *(const bf16x8*)(kbf + (size_t)(b * 2048 + j) * 512 + lane * 8);
    float d0 = (float)kk[0] * q0a.x + (float)kk[1] * q0a.y + (float)kk[2] * q0a.z + (float)kk[3] * q0a.w +
               (float)kk[4] * q0b.x + (float)kk[5] * q0b.y + (float)kk[6] * q0b.z + (float)kk[7] * q0b.w;
    float d1 = (float)kk[0] * q1a.x + (float)kk[1] * q1a.y + (float)kk[2] * q1a.z + (float)kk[3] * q1a.w +
               (float)kk[4] * q1b.x + (float)kk[5] * q1b.y + (float)kk[6] * q1b.z + (float)kk[7] * q1b.w;
    d0 = wave_red_sum(d0) * SCALE_;
    d1 = wave_red_sum(d1) * SCALE_;
    float mx = fmaxf(d0, d1);
    float e0 = __expf(d0 - mx), e1 = __expf(d1 - mx);
    float inv = 1.f / (e0 + e1);
    float p0 = e0 * inv, p1 = e1 * inv;
    rs0 += p0;
    rs1 += p1;
    bf16x8 vv = *(const bf16x8*)(vbf + (size_t)(b * 2048 + j) * 512 + lane * 8);
#pragma unroll
    for (int t = 0; t < 8; ++t) {
      float vf = (float)vv[t];
      u0[t] += p0 * vf;
      u1[t] += p1 * vf;
    }
    if (lane == 0) {
      attn_pre[(b * 2 + 0) * 2048 + j] = p0;
      attn_pre[(b * 2 + 1) * 2048 + j] = p1;
    }
  }
#pragma unroll
  for (int t = 0; t < 8; ++t) {
    atomicAdd(&upd[(b * 2 + 0) * 512 + lane * 8 + t], u0[t]);
    atomicAdd(&upd[(b * 2 + 1) * 512 + lane * 8 + t], u1[t]);
  }
  if (lane == 0) {
    atomicAdd(&rowsum[b * 2 + 0], rs0);
    atomicAdd(&rowsum[b * 2 + 1], rs1);
  }
}

// ---------------- gates: gx = u@wihT + bih, gh = h@whhT + bhh ----------------
// grid 384 = 32 rowgroups(2 rows) x 12 colchunks (0..5 gx, 6..11 gh); float4 cols, 4-wave split-K
__global__ __launch_bounds__(256) void gates_kernel(
    const float* __restrict__ slots, const float* __restrict__ upd,
    const float* __restrict__ rowsum,
    const float* __restrict__ wihT, const float* __restrict__ whhT,
    const float* __restrict__ bih, const float* __restrict__ bhh,
    float* __restrict__ gx, float* __restrict__ gh)
{
  __shared__ float in_s[2][512];
  __shared__ float part[4][2][256];
  int tid = threadIdx.x, w = tid >> 6, lane = tid & 63;
  int rg = blockIdx.x / 12, cc = blockIdx.x % 12;
  int is_gh = (cc >= 6);
  int ccl = is_gh ? cc - 6 : cc;
  // load inputs: 2 rows x 512
  {
    int rr = tid >> 7, pos = (tid & 127) * 4;
    int row = rg * 2 + rr;
    const float* src = (is_gh ? slots : upd) + row * 512;
    f32x4 v = *(const f32x4*)&src[pos];
    if (!is_gh) v *= 1.f / (rowsum[row] + EPS_);
    *(f32x4*)&in_s[rr][pos] = v;
  }
  __syncthreads();
  int c0 = ccl * 256 + lane * 4;
  const float* __restrict__ W = is_gh ? whhT : wihT;
  f32x4 acc0 = {0.f, 0.f, 0.f, 0.f}, acc1 = acc0;
  for (int d = w * 128; d < w * 128 + 128; ++d) {
    f32x4 w4 = *(const f32x4*)&W[d * 1536 + c0];
    acc0 += in_s[0][d] * w4;
    acc1 += in_s[1][d] * w4;
  }
  *(f32x4*)&part[w][0][lane * 4] = acc0;
  *(f32x4*)&part[w][1][lane * 4] = acc1;
  __syncthreads();
  if (tid < 128) {
    int r = tid >> 6, l = tid & 63;
    int cf = ccl * 256 + l * 4;
    f32x4 s = *(const f32x4*)&part[0][r][l * 4];
    s += *(const f32x4*)&part[1][r][l * 4];
    s += *(const f32x4*)&part[2][r][l * 4];
    s += *(const f32x4*)&part[3][r][l * 4];
    s += *(const f32x4*)&(is_gh ? bhh : bih)[cf];
    *(f32x4*)&(is_gh ? gh : gx)[(rg * 2 + r) * 1536 + cf] = s;
  }
}

// ---------------- GRU elementwise + LN -> hnew, hln ----------------
__global__ __launch_bounds__(512) void gru_ln_kernel(
    const float* __restrict__ gx, const float* __restrict__ gh,
    const float* __restrict__ slots,
    const float* __restrict__ lnf_g, const float* __restrict__ lnf_b,
    float* __restrict__ hnew, float* __restrict__ hln)
{
  __shared__ float red1[8], red2[8];
  int tid = threadIdx.x, row = blockIdx.x;
  float gxr = gx[row * 1536 + tid], gxz = gx[row * 1536 + 512 + tid], gxn = gx[row * 1536 + 1024 + tid];
  float ghr = gh[row * 1536 + tid], ghz = gh[row * 1536 + 512 + tid], ghn = gh[row * 1536 + 1024 + tid];
  float h = slots[row * 512 + tid];
  float r_ = 1.f / (1.f + __expf(-(gxr + ghr)));
  float z_ = 1.f / (1.f + __expf(-(gxz + ghz)));
  float n_ = tanhf(gxn + r_ * ghn);
  float hn = (1.f - z_) * n_ + z_ * h;
  hnew[row * 512 + tid] = hn;
  float s1 = wave_red_sum(hn), s2 = wave_red_sum(hn * hn);
  int w = tid >> 6, lane = tid & 63;
  if (lane == 0) { red1[w] = s1; red2[w] = s2; }
  __syncthreads();
  s1 = 0.f; s2 = 0.f;
#pragma unroll
  for (int i = 0; i < 8; ++i) { s1 += red1[i]; s2 += red2[i]; }
  float mean = s1 * (1.f / 512.f);
  float var = s2 * (1.f / 512.f) - mean * mean;
  float rstd = rsqrtf(var + LN_EPS);
  hln[row * 512 + tid] = (hn - mean) * rstd * lnf_g[tid] + lnf_b[tid];
}

// ---------------- mlp1: act = relu(hln @ W1 + b1); grid 256 = 32 rg x 8 cc ----------------
__global__ __launch_bounds__(256) void mlp1_kernel(
    const float* __restrict__ hln, const float* __restrict__ W1,
    const float* __restrict__ b1, float* __restrict__ act)
{
  __shared__ float in_s[2][512];
  __shared__ float part[4][2][64];
  int tid = threadIdx.x, w = tid >> 6, lane = tid & 63;
  int rg = blockIdx.x >> 3, cc = blockIdx.x & 7;
  {
    int rr = tid >> 7, pos = (tid & 127) * 4;
    *(f32x4*)&in_s[rr][pos] = *(const f32x4*)&hln[(rg * 2 + rr) * 512 + pos];
  }
  __syncthreads();
  int c = cc * 64 + lane;
  float a0 = 0.f, a1 = 0.f;
  for (int d = w * 128; d < w * 128 + 128; ++d) {
    float wv = W1[d * 512 + c];
    a0 += in_s[0][d] * wv;
    a1 += in_s[1][d] * wv;
  }
  part[w][0][lane] = a0;
  part[w][1][lane] = a1;
  __syncthreads();
  if (tid < 128) {
    int r = tid >> 6, l = tid & 63;
    float s = part[0][r][l] + part[1][r][l] + part[2][r][l] + part[3][r][l]
            + b1[cc * 64 + l];
    act[(rg * 2 + r) * 512 + cc * 64 + l] = fmaxf(s, 0.f);
  }
}

// ---------------- mlp2: slots = hnew + act @ W2 + b2; grid 256 ----------------
__global__ __launch_bounds__(256) void mlp2_kernel(
    const float* __restrict__ act, const float* __restrict__ W2,
    const float* __restrict__ b2, const float* __restrict__ hnew,
    float* __restrict__ slots)
{
  __shared__ float in_s[2][512];
  __shared__ float part[4][2][64];
  int tid = threadIdx.x, w = tid >> 6, lane = tid & 63;
  int rg = blockIdx.x >> 3, cc = blockIdx.x & 7;
  {
    int rr = tid >> 7, pos = (tid & 127) * 4;
    *(f32x4*)&in_s[rr][pos] = *(const f32x4*)&act[(rg * 2 + rr) * 512 + pos];
  }
  __syncthreads();
  int c = cc * 64 + lane;
  float a0 = 0.f, a1 = 0.f;
  for (int d = w * 128; d < w * 128 + 128; ++d) {
    float wv = W2[d * 512 + c];
    a0 += in_s[0][d] * wv;
    a1 += in_s[1][d] * wv;
  }
  part[w][0][lane] = a0;
  part[w][1][lane] = a1;
  __syncthreads();
  if (tid < 128) {
    int r = tid >> 6, l = tid & 63;
    int row = rg * 2 + r, c2 = cc * 64 + l;
    float s = part[0][r][l] + part[1][r][l] + part[2][r][l] + part[3][r][l] + b2[c2];
    slots[row * 512 + c2] = hnew[row * 512 + c2] + s;
  }
}

// ---------------- attn normalize in place ----------------
__global__ __launch_bounds__(256) void norm_attn(
    const float* __restrict__ rowsum, float* __restrict__ attn)
{
  int idx = blockIdx.x * 256 + threadIdx.x;  // < 131072
  int row = idx >> 11;
  attn[idx] = attn[idx] / (rowsum[row] + EPS_);
}

extern "C" void kernel_launch(void* const* d_in, const int* in_sizes, int n_in,
                              void* d_out, int out_size, void* d_ws, size_t ws_size,
                              hipStream_t stream)
{
  const float* inputs     = (const float*)d_in[0];
  const float* slots_init = (const float*)d_in[1];
  const float* Wq   = (const float*)d_in[2];
  const float* bq   = (const float*)d_in[3];
  const float* Wk   = (const float*)d_in[4];
  const float* bk   = (const float*)d_in[5];
  const float* Wv   = (const float*)d_in[6];
  const float* bv   = (const float*)d_in[7];
  const float* ln_in_g = (const float*)d_in[8];
  const float* ln_in_b = (const float*)d_in[9];
  const float* ln_s_g  = (const float*)d_in[10];
  const float* ln_s_b  = (const float*)d_in[11];
  const float* ln_f_g  = (const float*)d_in[12];
  const float* ln_f_b  = (const float*)d_in[13];
  const float* wih  = (const float*)d_in[14];
  const float* whh  = (const float*)d_in[15];
  const float* bih  = (const float*)d_in[16];
  const float* bhh  = (const float*)d_in[17];
  const float* W1   = (const float*)d_in[18];
  const float* b1   = (const float*)d_in[19];
  const float* W2   = (const float*)d_in[20];
  const float* b2   = (const float*)d_in[21];

  float* out   = (float*)d_out;
  float* slots = out;                 // [32,2,512] working + final output
  float* qreg  = out + 32768;         // [32,2,512] q (rewritten each iter; last persists)
  float* k_out = out + 65536;         // [32,2048,512] fp32 k
  float* attnp = out + 33619968;      // [32,2,2048] attn (pre, normalized in place at end)

  char* ws = (char*)d_ws;
  bf16_t* kbf   = (bf16_t*)(ws);                    // 67,108,864
  bf16_t* vbf   = (bf16_t*)(ws + 67108864);         // 67,108,864
  bf16_t* BT    = (bf16_t*)(ws + 134217728);        //  1,048,576 (dead after gemm)
  //   aliases after gemm:
  float*  gx    = (float*)(ws + 134217728);         //    393,216
  float*  gh    = (float*)(ws + 134610944);         //    393,216
  float*  hnew  = (float*)(ws + 135004160);         //    131,072
  float*  hln   = (float*)(ws + 135135232);         //    131,072
  float*  wihT  = (float*)(ws + 135266304);         //  3,145,728
  float*  whhT  = (float*)(ws + 138412032);         //  3,145,728
  float*  biasc = (float*)(ws + 141557760);         //      4,096
  float2* stats = (float2*)(ws + 141561856);        //    524,288 (dead after gemm)
  float*  act   = (float*)(ws + 141561856);         //    131,072 (alias)
  float*  upd   = (float*)(ws + 142086144);         //    131,072
  float*  rowsum= (float*)(ws + 142217216);         //        256  -> end 142,217,472

  transpose_prep<<<dim3(16, 48, 4), 256, 0, stream>>>(Wk, Wv, wih, whh, BT, wihT, whhT);
  small_prep<<<132, 256, 0, stream>>>(bk, bv, slots_init, biasc, slots);
  ln_stats<<<16384, 256, 0, stream>>>(inputs, stats);
  gemm_kv<<<dim3(8, 512), 256, 0, stream>>>(inputs, stats, ln_in_g, ln_in_b, BT, biasc,
                                            k_out, kbf, vbf);
  for (int it = 0; it < 3; ++it) {
    q_fused<<<128, 256, 0, stream>>>(slots, ln_s_g, ln_s_b, Wq, bq, qreg, upd, rowsum);
    attend_kernel<<<512, 256, 0, stream>>>(kbf, vbf, qreg, upd, rowsum, attnp);
    gates_kernel<<<384, 256, 0, stream>>>(slots, upd, rowsum, wihT, whhT, bih, bhh, gx, gh);
    gru_ln_kernel<<<64, 512, 0, stream>>>(gx, gh, slots, ln_f_g, ln_f_b, hnew, hln);
    mlp1_kernel<<<256, 256, 0, stream>>>(hln, W1, b1, act);
    mlp2_kernel<<<256, 256, 0, stream>>>(act, W2, b2, hnew, slots);
  }
  norm_attn<<<512, 256, 0, stream>>>(rowsum, attnp);
}

// Round 4
// 1012.675 us; speedup vs baseline: 1.6740x; 1.0252x over previous
//
#include <hip/hip_runtime.h>
#include <stdint.h>

typedef __bf16 bf16_t;
typedef bf16_t bf16x8 __attribute__((ext_vector_type(8)));
typedef float f32x4 __attribute__((ext_vector_type(4)));

typedef unsigned int u32;
typedef __attribute__((address_space(1))) const u32 gu32;
typedef __attribute__((address_space(3))) u32 lu32;

#define LN_EPS 1e-5f
#define EPS_ 1e-8f
#define SCALE_ 0.04419417382415922f  // 512^-0.5

__device__ __forceinline__ float wave_red_sum(float v) {
#pragma unroll
  for (int off = 32; off > 0; off >>= 1) v += __shfl_xor(v, off, 64);
  return v;
}

// ---------------- prep: LDS-tiled transposes (coalesced both sides) ----------------
__global__ __launch_bounds__(256) void transpose_prep(
    const float* __restrict__ Wk, const float* __restrict__ Wv,
    const float* __restrict__ wih, const float* __restrict__ whh,
    bf16_t* __restrict__ BT, float* __restrict__ wihT, float* __restrict__ whhT)
{
  int z = blockIdx.z;
  if (z < 2 && blockIdx.y >= 16) return;
  const float* src = (z == 0) ? Wk : (z == 1) ? Wv : (z == 2) ? wih : whh;
  __shared__ float tile[32][33];
  int tx = threadIdx.x & 31, ty = threadIdx.x >> 5;  // 32 x 8
  int row0 = blockIdx.y * 32, col0 = blockIdx.x * 32;
#pragma unroll
  for (int i = 0; i < 4; ++i)
    tile[ty + 8 * i][tx] = src[(size_t)(row0 + ty + 8 * i) * 512 + col0 + tx];
  __syncthreads();
  if (z < 2) {
#pragma unroll
    for (int i = 0; i < 4; ++i)
      BT[(size_t)(z * 512 + col0 + ty + 8 * i) * 512 + row0 + tx] =
          (bf16_t)tile[tx][ty + 8 * i];
  } else {
    float* dst = (z == 2) ? wihT : whhT;
#pragma unroll
    for (int i = 0; i < 4; ++i)
      dst[(size_t)(col0 + ty + 8 * i) * 1536 + row0 + tx] = tile[tx][ty + 8 * i];
  }
}

// ---------------- small prep: biasc pack + slots init (into d_out) ----------------
__global__ __launch_bounds__(256) void small_prep(
    const float* __restrict__ bk, const float* __restrict__ bv,
    const float* __restrict__ slots_init,
    float* __restrict__ biasc, float* __restrict__ slots)
{
  int idx = blockIdx.x * 256 + threadIdx.x;  // < 33792
  if (idx < 1024) {
    biasc[idx] = (idx < 512) ? bk[idx] : bv[idx - 512];
  } else {
    int i = idx - 1024;  // < 32768
    slots[i] = slots_init[i];
  }
}

// ---------------- per-row LN stats of inputs: (mean, rstd) ----------------
__global__ __launch_bounds__(256) void ln_stats(
    const float* __restrict__ in, float2* __restrict__ stats)
{
  int w = threadIdx.x >> 6, lane = threadIdx.x & 63;
  size_t row = (size_t)blockIdx.x * 4 + w;
  const float4* rp = (const float4*)(in + row * 512);
  float4 a = rp[lane * 2], c = rp[lane * 2 + 1];
  float s1 = a.x + a.y + a.z + a.w + c.x + c.y + c.z + c.w;
  float s2 = a.x * a.x + a.y * a.y + a.z * a.z + a.w * a.w +
             c.x * c.x + c.y * c.y + c.z * c.z + c.w * c.w;
  s1 = wave_red_sum(s1);
  s2 = wave_red_sum(s2);
  if (lane == 0) {
    float mean = s1 * (1.f / 512.f);
    float var = s2 * (1.f / 512.f) - mean * mean;
    stats[row] = make_float2(mean, rsqrtf(var + LN_EPS));
  }
}

// ---------------- fused LN + bf16 MFMA GEMM, XCD-swizzled ----------------
// 1-D grid 4096: x=l&7 (XCD), t=l>>3, n0=(t&7)*128, m0=((t>>3)*8+x)*128
// -> the 8 n-tiles of one m-strip land on one XCD; A strip stays in that L2.
__global__ __launch_bounds__(256) void gemm_kv(
    const float* __restrict__ inp, const float2* __restrict__ stats,
    const float* __restrict__ lng, const float* __restrict__ lnb,
    const bf16_t* __restrict__ BT, const float* __restrict__ biasc,
    float* __restrict__ out_k, bf16_t* __restrict__ kbf, bf16_t* __restrict__ vbf)
{
  __shared__ __align__(16) char smem[16384];
  bf16_t* As = (bf16_t*)smem;             // 128 x 32 bf16
  bf16_t* Bs = (bf16_t*)(smem + 8192);    // 128 x 32 bf16
  float (*Cs)[132] = (float(*)[132])smem; // 16 x 132 fp32 (epilogue reuse)

  const int tid = threadIdx.x, lane = tid & 63, w = tid >> 6;
  const int quad = lane >> 4, l16 = lane & 15;
  const int l = blockIdx.x;
  const int x = l & 7, t = l >> 3;
  const int n0 = (t & 7) * 128;
  const int m0 = ((t >> 3) * 8 + x) * 128;
  const int mb = (w & 1) * 64, nb = (w >> 1) * 64;

  const int rr = tid >> 1, c16 = (tid & 1) * 16;
  const float2 st = stats[m0 + rr];
  const float mu = st.x, rs = st.y;
  const float* arow = inp + (size_t)(m0 + rr) * 512;

  f32x4 acc[4][4] = {};

  for (int kk = 0; kk < 512; kk += 32) {
    const float* ap = arow + kk + c16;
    f32x4 x0 = *(const f32x4*)(ap);
    f32x4 x1 = *(const f32x4*)(ap + 4);
    f32x4 x2 = *(const f32x4*)(ap + 8);
    f32x4 x3 = *(const f32x4*)(ap + 12);
    const float* gp = lng + kk + c16;
    const float* bp = lnb + kk + c16;
    f32x4 g0 = *(const f32x4*)(gp), g1 = *(const f32x4*)(gp + 4);
    f32x4 g2 = *(const f32x4*)(gp + 8), g3 = *(const f32x4*)(gp + 12);
    f32x4 b0 = *(const f32x4*)(bp), b1 = *(const f32x4*)(bp + 4);
    f32x4 b2 = *(const f32x4*)(bp + 8), b3 = *(const f32x4*)(bp + 12);
    bf16x8 oA, oB;
#pragma unroll
    for (int j = 0; j < 4; ++j) {
      oA[j]     = (bf16_t)((x0[j] - mu) * rs * g0[j] + b0[j]);
      oA[4 + j] = (bf16_t)((x1[j] - mu) * rs * g1[j] + b1[j]);
      oB[j]     = (bf16_t)((x2[j] - mu) * rs * g2[j] + b2[j]);
      oB[4 + j] = (bf16_t)((x3[j] - mu) * rs * g3[j] + b3[j]);
    }
    *(bf16x8*)&As[rr * 32 + c16] = oA;
    *(bf16x8*)&As[rr * 32 + c16 + 8] = oB;
#pragma unroll
    for (int r = 0; r < 2; ++r) {
      int tt = tid + r * 256;
      int rrB = tt >> 2, ccB = (tt & 3) * 8;
      const bf16_t* gb = BT + (size_t)(n0 + rrB) * 512 + kk + ccB;
      __builtin_amdgcn_global_load_lds((gu32*)gb, (lu32*)&Bs[tt * 8], 16, 0, 0);
    }
    __syncthreads();
    bf16x8 af[4], bfr[4];
#pragma unroll
    for (int mt = 0; mt < 4; ++mt)
      af[mt] = *(const bf16x8*)&As[(mb + mt * 16 + l16) * 32 + quad * 8];
#pragma unroll
    for (int nt = 0; nt < 4; ++nt)
      bfr[nt] = *(const bf16x8*)&Bs[(nb + nt * 16 + l16) * 32 + quad * 8];
#pragma unroll
    for (int mt = 0; mt < 4; ++mt)
#pragma unroll
      for (int nt = 0; nt < 4; ++nt)
        acc[mt][nt] = __builtin_amdgcn_mfma_f32_16x16x32_bf16(af[mt], bfr[nt], acc[mt][nt], 0, 0, 0);
    __syncthreads();
  }

  const int is_k = (n0 < 512);
  const int col4 = (tid * 4) & 127;
  const int row8 = tid >> 4;
  const int col8 = (tid * 8) & 127;
  for (int ci = 0; ci < 8; ++ci) {
    if ((ci < 4) == (mb == 0)) {
      int mt = ci & 3;
#pragma unroll
      for (int nt = 0; nt < 4; ++nt)
#pragma unroll
        for (int r = 0; r < 4; ++r)
          Cs[quad * 4 + r][nb + nt * 16 + l16] = acc[mt][nt][r];
    }
    __syncthreads();
    int rowbase = m0 + ci * 16;
    if (is_k) {
      f32x4 bias4 = *(const f32x4*)&biasc[n0 + col4];
#pragma unroll
      for (int p = 0; p < 2; ++p) {
        int f = p * 1024 + tid * 4;
        int row = f >> 7;
        f32x4 v = *(const f32x4*)&Cs[row][col4] + bias4;
        *(f32x4*)&out_k[(size_t)(rowbase + row) * 512 + n0 + col4] = v;
      }
      f32x4 ba = *(const f32x4*)&biasc[n0 + col8];
      f32x4 bb = *(const f32x4*)&biasc[n0 + col8 + 4];
      f32x4 v0 = *(const f32x4*)&Cs[row8][col8] + ba;
      f32x4 v1 = *(const f32x4*)&Cs[row8][col8 + 4] + bb;
      bf16x8 o;
#pragma unroll
      for (int j = 0; j < 4; ++j) { o[j] = (bf16_t)v0[j]; o[4 + j] = (bf16_t)v1[j]; }
      *(bf16x8*)&kbf[(size_t)(rowbase + row8) * 512 + n0 + col8] = o;
    } else {
      f32x4 ba = *(const f32x4*)&biasc[n0 + col8];
      f32x4 bb = *(const f32x4*)&biasc[n0 + col8 + 4];
      f32x4 v0 = *(const f32x4*)&Cs[row8][col8] + ba;
      f32x4 v1 = *(const f32x4*)&Cs[row8][col8 + 4] + bb;
      bf16x8 o;
#pragma unroll
      for (int j = 0; j < 4; ++j) { o[j] = (bf16_t)v0[j]; o[4 + j] = (bf16_t)v1[j]; }
      *(bf16x8*)&vbf[(size_t)(rowbase + row8) * 512 + (n0 - 512) + col8] = o;
    }
    __syncthreads();
  }
}

// ---------------- attend: inline LN(slots)+q, then dots -> softmax -> weighted-v ----------------
// grid 512 = 32 b x 16 chunk; upd/rowsum pre-zeroed by memset
__global__ __launch_bounds__(256) void attend_fused(
    const bf16_t* __restrict__ kbf, const bf16_t* __restrict__ vbf,
    const float* __restrict__ slots,
    const float* __restrict__ lnsg, const float* __restrict__ lnsb,
    const float* __restrict__ Wq, const float* __restrict__ bq,
    float* __restrict__ upd, float* __restrict__ rowsum,
    float* __restrict__ q_out, float* __restrict__ attn_pre)
{
  __shared__ float s[2][512];
  __shared__ float qs[2][512];
  __shared__ float red1[4], red2[4];
  int tid = threadIdx.x, w = tid >> 6, lane = tid & 63;
  int b = blockIdx.x >> 4, chunk = blockIdx.x & 15;

  // ---- LN(slots rows 2b, 2b+1) ----
  int r = tid >> 7;                 // row within pair
  int off = (tid * 4) & 511;
  float4 v = *(const float4*)&slots[b * 1024 + tid * 4];
  float s1 = v.x + v.y + v.z + v.w;
  float s2 = v.x * v.x + v.y * v.y + v.z * v.z + v.w * v.w;
  s1 = wave_red_sum(s1);
  s2 = wave_red_sum(s2);
  if (lane == 0) { red1[w] = s1; red2[w] = s2; }
  __syncthreads();
  float mean = (red1[r * 2] + red1[r * 2 + 1]) * (1.f / 512.f);
  float var = (red2[r * 2] + red2[r * 2 + 1]) * (1.f / 512.f) - mean * mean;
  float rstd = rsqrtf(var + LN_EPS);
  float4 g4 = *(const float4*)&lnsg[off];
  float4 b4 = *(const float4*)&lnsb[off];
  s[r][off + 0] = (v.x - mean) * rstd * g4.x + b4.x;
  s[r][off + 1] = (v.y - mean) * rstd * g4.y + b4.y;
  s[r][off + 2] = (v.z - mean) * rstd * g4.z + b4.z;
  s[r][off + 3] = (v.w - mean) * rstd * g4.w + b4.w;
  __syncthreads();

  // ---- q GEMV: cols tid*2, tid*2+1 for both rows ----
  int c = tid * 2;
  float a0 = 0.f, a1 = 0.f, a2 = 0.f, a3 = 0.f;
#pragma unroll 4
  for (int d = 0; d < 512; ++d) {
    float2 wv = *(const float2*)&Wq[d * 512 + c];
    float s0d = s[0][d], s1d = s[1][d];
    a0 += s0d * wv.x; a1 += s0d * wv.y;
    a2 += s1d * wv.x; a3 += s1d * wv.y;
  }
  float2 bq2 = *(const float2*)&bq[c];
  qs[0][c] = a0 + bq2.x; qs[0][c + 1] = a1 + bq2.y;
  qs[1][c] = a2 + bq2.x; qs[1][c + 1] = a3 + bq2.y;
  __syncthreads();
  if (chunk == 0) {
    const float* qf = &qs[0][0];
    *(f32x4*)&q_out[b * 1024 + tid * 4] = *(const f32x4*)&qf[tid * 4];
  }
  float4 q0a = *(const float4*)&qs[0][lane * 8];
  float4 q0b = *(const float4*)&qs[0][lane * 8 + 4];
  float4 q1a = *(const float4*)&qs[1][lane * 8];
  float4 q1b = *(const float4*)&qs[1][lane * 8 + 4];

  // ---- attend over 32 j's per wave ----
  int j0 = chunk * 128 + w * 32;
  float u0[8] = {}, u1[8] = {};
  float rs0 = 0.f, rs1 = 0.f;
  for (int jj = 0; jj < 32; ++jj) {
    int j = j0 + jj;
    bf16x8 kk = *(const bf16x8*)(kbf + (size_t)(b * 2048 + j) * 512 + lane * 8);
    float d0 = (float)kk[0] * q0a.x + (float)kk[1] * q0a.y + (float)kk[2] * q0a.z + (float)kk[3] * q0a.w +
               (float)kk[4] * q0b.x + (float)kk[5] * q0b.y + (float)kk[6] * q0b.z + (float)kk[7] * q0b.w;
    float d1 = (float)kk[0] * q1a.x + (float)kk[1] * q1a.y + (float)kk[2] * q1a.z + (float)kk[3] * q1a.w +
               (float)kk[4] * q1b.x + (float)kk[5] * q1b.y + (float)kk[6] * q1b.z + (float)kk[7] * q1b.w;
    d0 = wave_red_sum(d0) * SCALE_;
    d1 = wave_red_sum(d1) * SCALE_;
    float mx = fmaxf(d0, d1);
    float e0 = __expf(d0 - mx), e1 = __expf(d1 - mx);
    float inv = 1.f / (e0 + e1);
    float p0 = e0 * inv, p1 = e1 * inv;
    rs0 += p0;
    rs1 += p1;
    bf16x8 vv = *(const bf16x8*)(vbf + (size_t)(b * 2048 + j) * 512 + lane * 8);
#pragma unroll
    for (int tt = 0; tt < 8; ++tt) {
      float vf = (float)vv[tt];
      u0[tt] += p0 * vf;
      u1[tt] += p1 * vf;
    }
    if (lane == 0) {
      attn_pre[(b * 2 + 0) * 2048 + j] = p0;
      attn_pre[(b * 2 + 1) * 2048 + j] = p1;
    }
  }
#pragma unroll
  for (int tt = 0; tt < 8; ++tt) {
    atomicAdd(&upd[(b * 2 + 0) * 512 + lane * 8 + tt], u0[tt]);
    atomicAdd(&upd[(b * 2 + 1) * 512 + lane * 8 + tt], u1[tt]);
  }
  if (lane == 0) {
    atomicAdd(&rowsum[b * 2 + 0], rs0);
    atomicAdd(&rowsum[b * 2 + 1], rs1);
  }
}

// ---------------- gates: gx = u@wihT + bih, gh = h@whhT + bhh ----------------
__global__ __launch_bounds__(256) void gates_kernel(
    const float* __restrict__ slots, const float* __restrict__ upd,
    const float* __restrict__ rowsum,
    const float* __restrict__ wihT, const float* __restrict__ whhT,
    const float* __restrict__ bih, const float* __restrict__ bhh,
    float* __restrict__ gx, float* __restrict__ gh)
{
  __shared__ float in_s[2][512];
  __shared__ float part[4][2][256];
  int tid = threadIdx.x, w = tid >> 6, lane = tid & 63;
  int rg = blockIdx.x / 12, cc = blockIdx.x % 12;
  int is_gh = (cc >= 6);
  int ccl = is_gh ? cc - 6 : cc;
  {
    int rr = tid >> 7, pos = (tid & 127) * 4;
    int row = rg * 2 + rr;
    const float* src = (is_gh ? slots : upd) + row * 512;
    f32x4 v = *(const f32x4*)&src[pos];
    if (!is_gh) v *= 1.f / (rowsum[row] + EPS_);
    *(f32x4*)&in_s[rr][pos] = v;
  }
  __syncthreads();
  int c0 = ccl * 256 + lane * 4;
  const float* __restrict__ W = is_gh ? whhT : wihT;
  f32x4 acc0 = {0.f, 0.f, 0.f, 0.f}, acc1 = acc0;
  for (int d = w * 128; d < w * 128 + 128; ++d) {
    f32x4 w4 = *(const f32x4*)&W[d * 1536 + c0];
    acc0 += in_s[0][d] * w4;
    acc1 += in_s[1][d] * w4;
  }
  *(f32x4*)&part[w][0][lane * 4] = acc0;
  *(f32x4*)&part[w][1][lane * 4] = acc1;
  __syncthreads();
  if (tid < 128) {
    int r = tid >> 6, ll = tid & 63;
    int cf = ccl * 256 + ll * 4;
    f32x4 s = *(const f32x4*)&part[0][r][ll * 4];
    s += *(const f32x4*)&part[1][r][ll * 4];
    s += *(const f32x4*)&part[2][r][ll * 4];
    s += *(const f32x4*)&part[3][r][ll * 4];
    s += *(const f32x4*)&(is_gh ? bhh : bih)[cf];
    *(f32x4*)&(is_gh ? gh : gx)[(rg * 2 + r) * 1536 + cf] = s;
  }
}

// ---------------- GRU elementwise + LN -> hnew, hln ----------------
__global__ __launch_bounds__(512) void gru_ln_kernel(
    const float* __restrict__ gx, const float* __restrict__ gh,
    const float* __restrict__ slots,
    const float* __restrict__ lnf_g, const float* __restrict__ lnf_b,
    float* __restrict__ hnew, float* __restrict__ hln)
{
  __shared__ float red1[8], red2[8];
  int tid = threadIdx.x, row = blockIdx.x;
  float gxr = gx[row * 1536 + tid], gxz = gx[row * 1536 + 512 + tid], gxn = gx[row * 1536 + 1024 + tid];
  float ghr = gh[row * 1536 + tid], ghz = gh[row * 1536 + 512 + tid], ghn = gh[row * 1536 + 1024 + tid];
  float h = slots[row * 512 + tid];
  float r_ = 1.f / (1.f + __expf(-(gxr + ghr)));
  float z_ = 1.f / (1.f + __expf(-(gxz + ghz)));
  float n_ = tanhf(gxn + r_ * ghn);
  float hn = (1.f - z_) * n_ + z_ * h;
  hnew[row * 512 + tid] = hn;
  float s1 = wave_red_sum(hn), s2 = wave_red_sum(hn * hn);
  int w = tid >> 6, lane = tid & 63;
  if (lane == 0) { red1[w] = s1; red2[w] = s2; }
  __syncthreads();
  s1 = 0.f; s2 = 0.f;
#pragma unroll
  for (int i = 0; i < 8; ++i) { s1 += red1[i]; s2 += red2[i]; }
  float mean = s1 * (1.f / 512.f);
  float var = s2 * (1.f / 512.f) - mean * mean;
  float rstd = rsqrtf(var + LN_EPS);
  hln[row * 512 + tid] = (hn - mean) * rstd * lnf_g[tid] + lnf_b[tid];
}

// ---------------- mlp1: act = relu(hln @ W1 + b1) ----------------
__global__ __launch_bounds__(256) void mlp1_kernel(
    const float* __restrict__ hln, const float* __restrict__ W1,
    const float* __restrict__ b1, float* __restrict__ act)
{
  __shared__ float in_s[2][512];
  __shared__ float part[4][2][64];
  int tid = threadIdx.x, w = tid >> 6, lane = tid & 63;
  int rg = blockIdx.x >> 3, cc = blockIdx.x & 7;
  {
    int rr = tid >> 7, pos = (tid & 127) * 4;
    *(f32x4*)&in_s[rr][pos] = *(const f32x4*)&hln[(rg * 2 + rr) * 512 + pos];
  }
  __syncthreads();
  int c = cc * 64 + lane;
  float a0 = 0.f, a1 = 0.f;
  for (int d = w * 128; d < w * 128 + 128; ++d) {
    float wv = W1[d * 512 + c];
    a0 += in_s[0][d] * wv;
    a1 += in_s[1][d] * wv;
  }
  part[w][0][lane] = a0;
  part[w][1][lane] = a1;
  __syncthreads();
  if (tid < 128) {
    int r = tid >> 6, ll = tid & 63;
    float s = part[0][r][ll] + part[1][r][ll] + part[2][r][ll] + part[3][r][ll]
            + b1[cc * 64 + ll];
    act[(rg * 2 + r) * 512 + cc * 64 + ll] = fmaxf(s, 0.f);
  }
}

// ---------------- mlp2: slots = hnew + act @ W2 + b2 ----------------
__global__ __launch_bounds__(256) void mlp2_kernel(
    const float* __restrict__ act, const float* __restrict__ W2,
    const float* __restrict__ b2, const float* __restrict__ hnew,
    float* __restrict__ slots)
{
  __shared__ float in_s[2][512];
  __shared__ float part[4][2][64];
  int tid = threadIdx.x, w = tid >> 6, lane = tid & 63;
  int rg = blockIdx.x >> 3, cc = blockIdx.x & 7;
  {
    int rr = tid >> 7, pos = (tid & 127) * 4;
    *(f32x4*)&in_s[rr][pos] = *(const f32x4*)&act[(rg * 2 + rr) * 512 + pos];
  }
  __syncthreads();
  int c = cc * 64 + lane;
  float a0 = 0.f, a1 = 0.f;
  for (int d = w * 128; d < w * 128 + 128; ++d) {
    float wv = W2[d * 512 + c];
    a0 += in_s[0][d] * wv;
    a1 += in_s[1][d] * wv;
  }
  part[w][0][lane] = a0;
  part[w][1][lane] = a1;
  __syncthreads();
  if (tid < 128) {
    int r = tid >> 6, ll = tid & 63;
    int row = rg * 2 + r, c2 = cc * 64 + ll;
    float s = part[0][r][ll] + part[1][r][ll] + part[2][r][ll] + part[3][r][ll] + b2[c2];
    slots[row * 512 + c2] = hnew[row * 512 + c2] + s;
  }
}

// ---------------- attn normalize in place ----------------
__global__ __launch_bounds__(256) void norm_attn(
    const float* __restrict__ rowsum, float* __restrict__ attn)
{
  int idx = blockIdx.x * 256 + threadIdx.x;  // < 131072
  int row = idx >> 11;
  attn[idx] = attn[idx] / (rowsum[row] + EPS_);
}

extern "C" void kernel_launch(void* const* d_in, const int* in_sizes, int n_in,
                              void* d_out, int out_size, void* d_ws, size_t ws_size,
                              hipStream_t stream)
{
  const float* inputs     = (const float*)d_in[0];
  const float* slots_init = (const float*)d_in[1];
  const float* Wq   = (const float*)d_in[2];
  const float* bq   = (const float*)d_in[3];
  const float* Wk   = (const float*)d_in[4];
  const float* bk   = (const float*)d_in[5];
  const float* Wv   = (const float*)d_in[6];
  const float* bv   = (const float*)d_in[7];
  const float* ln_in_g = (const float*)d_in[8];
  const float* ln_in_b = (const float*)d_in[9];
  const float* ln_s_g  = (const float*)d_in[10];
  const float* ln_s_b  = (const float*)d_in[11];
  const float* ln_f_g  = (const float*)d_in[12];
  const float* ln_f_b  = (const float*)d_in[13];
  const float* wih  = (const float*)d_in[14];
  const float* whh  = (const float*)d_in[15];
  const float* bih  = (const float*)d_in[16];
  const float* bhh  = (const float*)d_in[17];
  const float* W1   = (const float*)d_in[18];
  const float* b1   = (const float*)d_in[19];
  const float* W2   = (const float*)d_in[20];
  const float* b2   = (const float*)d_in[21];

  float* out   = (float*)d_out;
  float* slots = out;                 // [32,2,512] working + final output
  float* q_out = out + 32768;         // [32,2,512]
  float* k_out = out + 65536;         // [32,2048,512] fp32 k
  float* attnp = out + 33619968;      // [32,2,2048] attn (normalized at end)

  char* ws = (char*)d_ws;
  bf16_t* kbf   = (bf16_t*)(ws);                    // 67,108,864
  bf16_t* vbf   = (bf16_t*)(ws + 67108864);         // 67,108,864
  bf16_t* BT    = (bf16_t*)(ws + 134217728);        //  1,048,576 (dead after gemm)
  float*  gx    = (float*)(ws + 134217728);         //    393,216 (alias)
  float*  gh    = (float*)(ws + 134610944);         //    393,216
  float*  hnew  = (float*)(ws + 135004160);         //    131,072
  float*  hln   = (float*)(ws + 135135232);         //    131,072
  float*  wihT  = (float*)(ws + 135266304);         //  3,145,728
  float*  whhT  = (float*)(ws + 138412032);         //  3,145,728
  float*  biasc = (float*)(ws + 141557760);         //      4,096
  float2* stats = (float2*)(ws + 141561856);        //    524,288 (dead after gemm)
  float*  act   = (float*)(ws + 141561856);         //    131,072 (alias)
  float*  upd   = (float*)(ws + 142086144);         //    131,072
  float*  rowsum= (float*)(ws + 142217216);         //        256  -> end 142,217,472

  transpose_prep<<<dim3(16, 48, 4), 256, 0, stream>>>(Wk, Wv, wih, whh, BT, wihT, whhT);
  small_prep<<<132, 256, 0, stream>>>(bk, bv, slots_init, biasc, slots);
  ln_stats<<<16384, 256, 0, stream>>>(inputs, stats);
  gemm_kv<<<4096, 256, 0, stream>>>(inputs, stats, ln_in_g, ln_in_b, BT, biasc,
                                    k_out, kbf, vbf);
  for (int it = 0; it < 3; ++it) {
    hipMemsetAsync(upd, 0, 131072 + 256, stream);  // zero upd + rowsum
    attend_fused<<<512, 256, 0, stream>>>(kbf, vbf, slots, ln_s_g, ln_s_b, Wq, bq,
                                          upd, rowsum, q_out, attnp);
    gates_kernel<<<384, 256, 0, stream>>>(slots, upd, rowsum, wihT, whhT, bih, bhh, gx, gh);
    gru_ln_kernel<<<64, 512, 0, stream>>>(gx, gh, slots, ln_f_g, ln_f_b, hnew, hln);
    mlp1_kernel<<<256, 256, 0, stream>>>(hln, W1, b1, act);
    mlp2_kernel<<<256, 256, 0, stream>>>(act, W2, b2, hnew, slots);
  }
  norm_attn<<<512, 256, 0, stream>>>(rowsum, attnp);
}